// Round 2
// baseline (2049.300 us; speedup 1.0000x reference)
//
#include <hip/hip_runtime.h>

// numpy-fp32 semantics: explicit fmaf only, no implicit contraction.
#pragma clang fp contract(off)

typedef unsigned char u8;
typedef unsigned int u32;

#define TSTEPS 4

// Fused (1x1 conv) + BN + LIF, fp32, bit-exact ascending-k FMA chain.
// LDS-free: W read in native [o][k] layout as float4 along k (k-groups of 4),
// x read as float4/u32 along n.  Both served by L1/L2; register pipeline D
// groups deep.  Tile 64o x 64n, 256 thr, 4x4/thread.  No barriers.
// XMODE: 0 = X1 fp32, 1 = X1 u8 spikes. HASX2: add u8 X2 (fc1: x+attn_out).
// OMODE: 0 = u8 spike out; 1 = fused final out_f32 = (x + ao) + spike.
template <int XMODE, bool HASX2, int OMODE>
__global__ __launch_bounds__(256) void conv_bn_lif(
    const void* __restrict__ X1v, const u8* __restrict__ X2,
    const float* __restrict__ Wt, const float* __restrict__ bias,
    const float* __restrict__ bnp,
    u8* __restrict__ Sout,
    const float* __restrict__ Xres, const u8* __restrict__ AOres,
    float* __restrict__ Fout,
    int Bsz, int Cin, int Cout, int N)
{
  const int tid = threadIdx.x;
  const int tx = tid & 15, ty = tid >> 4;
  const int nBase = blockIdx.x * 64, oBase = blockIdx.y * 64, b = blockIdx.z;

  // BN constants, correctly-rounded fp32 (double emu exact for add/sqrt/div)
  float sc[4], mn[4], bt[4], bi[4];
  #pragma unroll
  for (int i = 0; i < 4; ++i) {
    int o = oBase + ty * 4 + i;
    float g  = bnp[0 * Cout + o];
    float be = bnp[1 * Cout + o];
    float m  = bnp[2 * Cout + o];
    float vv = bnp[3 * Cout + o];
    float d_f = (float)((double)vv + (double)1e-5f);
    float s_f = (float)sqrt((double)d_f);
    sc[i] = (float)((double)g / (double)s_f);
    mn[i] = m; bt[i] = be;
    bi[i] = bias ? bias[o] : 0.0f;
  }

  float mem[4][4], acc[4][4];
  #pragma unroll
  for (int i = 0; i < 4; ++i)
    #pragma unroll
    for (int j = 0; j < 4; ++j) { mem[i][j] = 0.0f; acc[i][j] = 0.0f; }

  const int nOff = nBase + tx * 4;

  // W row pointers for this thread's 4 output channels (wave-uniform per ty).
  const float* Wr[4];
  #pragma unroll
  for (int i = 0; i < 4; ++i)
    Wr[i] = Wt + (size_t)(oBase + ty * 4 + i) * Cin;

  // Pipeline depth in 4-k groups. u8 inputs are cheap on VGPRs -> deeper.
  constexpr int D = (XMODE == 1) ? 4 : 2;
  const int NG = Cin >> 2;            // 4-k groups; Cin % (4*D) == 0 here

  float4 wb[D][4];                    // [slot][o-row]  W[o][4g..4g+3]
  float4 xb[D][4];                    // [slot][kk]     XMODE 0
  u32    xu[D][4];                    // [slot][kk]     XMODE 1
  u32    au[D][4];                    // [slot][kk]     HASX2

  for (int t = 0; t < TSTEPS; ++t) {
    const float* xT0 = nullptr;
    const u8*    xT1 = nullptr;
    if constexpr (XMODE == 0)
      xT0 = (const float*)X1v + (size_t)(t * Bsz + b) * Cin * N + nOff;
    else
      xT1 = (const u8*)X1v + (size_t)(t * Bsz + b) * Cin * N + nOff;
    const u8* aT = nullptr;
    if constexpr (HASX2)
      aT = X2 + (size_t)(t * Bsz + b) * Cin * N + nOff;

    auto LOAD = [&](int d, int g) {
      #pragma unroll
      for (int i = 0; i < 4; ++i)
        wb[d][i] = *(const float4*)(Wr[i] + 4 * g);
      #pragma unroll
      for (int kk = 0; kk < 4; ++kk) {
        if constexpr (XMODE == 0)
          xb[d][kk] = *(const float4*)(xT0 + (size_t)(4 * g + kk) * N);
        else
          xu[d][kk] = *(const u32*)(xT1 + (size_t)(4 * g + kk) * N);
        if constexpr (HASX2)
          au[d][kk] = *(const u32*)(aT + (size_t)(4 * g + kk) * N);
      }
    };

    auto COMP = [&](int d) {
      #pragma unroll
      for (int kk = 0; kk < 4; ++kk) {          // ascending k within group
        float xa[4];
        if constexpr (XMODE == 0) {
          float4 xv = xb[d][kk];
          xa[0] = xv.x; xa[1] = xv.y; xa[2] = xv.z; xa[3] = xv.w;
        } else {
          u32 u = xu[d][kk];
          #pragma unroll
          for (int j = 0; j < 4; ++j) xa[j] = (float)((u >> (8 * j)) & 0xffu);
        }
        if constexpr (HASX2) {
          u32 a2 = au[d][kk];
          #pragma unroll
          for (int j = 0; j < 4; ++j)
            xa[j] = xa[j] + (float)((a2 >> (8 * j)) & 0xffu);
        }
        #pragma unroll
        for (int i = 0; i < 4; ++i) {
          const float4 wq = wb[d][i];
          const float wa = (kk == 0) ? wq.x : (kk == 1) ? wq.y
                         : (kk == 2) ? wq.z : wq.w;      // folds: kk is const
          #pragma unroll
          for (int j = 0; j < 4; ++j)
            acc[i][j] = fmaf(wa, xa[j], acc[i][j]);      // bit-exact chain
        }
      }
    };

    // prime the pipeline
    #pragma unroll
    for (int d = 0; d < D; ++d) LOAD(d, d);
    // steady state: compute group, prefetch group+D
    for (int g = 0; g < NG - D; g += D) {
      #pragma unroll
      for (int d = 0; d < D; ++d) { COMP(d); LOAD(d, g + d + D); }
    }
    // drain tail
    #pragma unroll
    for (int d = 0; d < D; ++d) COMP(d);

    // epilogue for timestep t (identical op order to the verified kernel)
    const size_t sbase = (size_t)(t * Bsz + b) * Cout * N;
    #pragma unroll
    for (int i = 0; i < 4; ++i) {
      const size_t rb = sbase + (size_t)(oBase + ty * 4 + i) * N + nBase + tx * 4;
      if constexpr (OMODE == 0) {
        u32 pack = 0;
        #pragma unroll
        for (int j = 0; j < 4; ++j) {
          float y = acc[i][j];
          if (bias) y = y + bi[i];
          float t1 = y - mn[i];
          float t2 = t1 * sc[i];
          y = t2 + bt[i];
          float m2 = mem[i][j];
          float dd = y - m2;
          m2 = m2 + dd * 0.5f;
          bool sp = (m2 - 0.5f) > 0.0f;
          mem[i][j] = sp ? 0.0f : m2;
          if (sp) pack |= (1u << (8 * j));
          acc[i][j] = 0.0f;
        }
        *(u32*)&Sout[rb] = pack;
      } else {
        float4 xr = *(const float4*)&Xres[rb];
        u32 av = *(const u32*)&AOres[rb];
        float xa4[4] = {xr.x, xr.y, xr.z, xr.w};
        float o4[4];
        #pragma unroll
        for (int j = 0; j < 4; ++j) {
          float y = acc[i][j];
          if (bias) y = y + bi[i];
          float t1 = y - mn[i];
          float t2 = t1 * sc[i];
          y = t2 + bt[i];
          float m2 = mem[i][j];
          float dd = y - m2;
          m2 = m2 + dd * 0.5f;
          bool sp = (m2 - 0.5f) > 0.0f;
          mem[i][j] = sp ? 0.0f : m2;
          float s = sp ? 1.0f : 0.0f;
          float xn = xa4[j] + (float)((av >> (8 * j)) & 0xffu);
          o4[j] = xn + s;
          acc[i][j] = 0.0f;
        }
        *(float4*)&Fout[rb] = make_float4(o4[0], o4[1], o4[2], o4[3]);
      }
    }
  }
}

// Attention + attn-LIF, q @ (k^T v): integer-exact (unchanged, verified).
__global__ __launch_bounds__(256) void attn_lif(
    const u8* __restrict__ Qs, const u8* __restrict__ Ks,
    const u8* __restrict__ Vs, u8* __restrict__ Rs,
    int Bsz, int C, int N)
{
  const int tid = threadIdx.x;
  const int h = blockIdx.x & 15;
  const int b = blockIdx.x >> 4;

  __shared__ u8 qs[16][528];
  __shared__ u8 ks[16][528];
  __shared__ u8 vs[16][528];
  __shared__ int Gs[16][17];

  const int eG = tid >> 4;
  const int dG = tid & 15;
  const int dR = tid >> 4;
  const int nR0 = tid & 15;

  float mem[32];
  #pragma unroll
  for (int i = 0; i < 32; ++i) mem[i] = 0.0f;

  for (int t = 0; t < TSTEPS; ++t) {
    __syncthreads();
    const size_t base = ((size_t)(t * Bsz + b) * C + h * 16) * N;
    for (int i = 0; i < 32; ++i) {
      int flat = tid + 256 * i;
      int d = flat >> 9, n = flat & 511;
      size_t g = base + (size_t)d * N + n;
      qs[d][n] = Qs[g];
      ks[d][n] = Ks[g];
      vs[d][n] = Vs[g];
    }
    __syncthreads();

    int gi = 0;
    for (int n = 0; n < 512; ++n)
      gi += (int)ks[eG][n] * (int)vs[dG][n];
    Gs[eG][dG] = gi;
    __syncthreads();

    int Greg[16];
    #pragma unroll
    for (int e = 0; e < 16; ++e) Greg[e] = Gs[e][dR];

    const size_t obase = ((size_t)(t * Bsz + b) * C + h * 16 + dR) * N;
    for (int j = 0; j < 32; ++j) {
      int n = nR0 + 16 * j;
      int ri = 0;
      #pragma unroll
      for (int e = 0; e < 16; ++e)
        ri += qs[e][n] ? Greg[e] : 0;
      float r = (float)ri * 0.0625f;
      float m2 = mem[j];
      float d = r - m2;
      m2 = m2 + d * 0.5f;
      float s = (m2 - 0.5f) > 0.0f ? 1.0f : 0.0f;
      mem[j] = (s > 0.0f) ? 0.0f : m2;
      Rs[obase + n] = (s > 0.0f) ? (u8)1 : (u8)0;
    }
  }
}

extern "C" void kernel_launch(void* const* d_in, const int* in_sizes, int n_in,
                              void* d_out, int out_size, void* d_ws, size_t ws_size,
                              hipStream_t stream)
{
  const float* x     = (const float*)d_in[0];
  const float* q_w   = (const float*)d_in[1];
  const float* q_bn  = (const float*)d_in[2];
  const float* k_w   = (const float*)d_in[3];
  const float* k_bn  = (const float*)d_in[4];
  const float* v_w   = (const float*)d_in[5];
  const float* v_bn  = (const float*)d_in[6];
  const float* p_w   = (const float*)d_in[7];
  const float* p_bn  = (const float*)d_in[8];
  const float* f1_w  = (const float*)d_in[9];
  const float* f1_b  = (const float*)d_in[10];
  const float* f1_bn = (const float*)d_in[11];
  const float* f2_w  = (const float*)d_in[12];
  const float* f2_b  = (const float*)d_in[13];
  const float* f2_bn = (const float*)d_in[14];

  const int T = 4, B = 16, C = 256, N = 512, Hm = 1024;
  const size_t SZ = (size_t)T * B * C * N;  // u8 spike buffers (8.4 MB)

  // Workspace (u8), peak 5*SZ = 41.9 MB; h (4*SZ) overlays dead q/k/v/r.
  char* ws = (char*)d_ws;
  u8* q_s  = (u8*)(ws + 0 * SZ);
  u8* k_s  = (u8*)(ws + 1 * SZ);
  u8* v_s  = (u8*)(ws + 2 * SZ);
  u8* r_s  = (u8*)(ws + 3 * SZ);
  u8* ao_s = (u8*)(ws + 4 * SZ);
  u8* h_s  = (u8*)(ws + 0 * SZ);

  dim3 blk(256);
  dim3 gC(N / 64, C / 64, B);

  conv_bn_lif<0, false, 0><<<gC, blk, 0, stream>>>(
      x, nullptr, q_w, nullptr, q_bn, q_s, nullptr, nullptr, nullptr, B, C, C, N);
  conv_bn_lif<0, false, 0><<<gC, blk, 0, stream>>>(
      x, nullptr, k_w, nullptr, k_bn, k_s, nullptr, nullptr, nullptr, B, C, C, N);
  conv_bn_lif<0, false, 0><<<gC, blk, 0, stream>>>(
      x, nullptr, v_w, nullptr, v_bn, v_s, nullptr, nullptr, nullptr, B, C, C, N);

  attn_lif<<<dim3(B * 16), blk, 0, stream>>>(q_s, k_s, v_s, r_s, B, C, N);

  conv_bn_lif<1, false, 0><<<gC, blk, 0, stream>>>(
      r_s, nullptr, p_w, nullptr, p_bn, ao_s, nullptr, nullptr, nullptr, B, C, C, N);
  conv_bn_lif<0, true, 0><<<dim3(N / 64, Hm / 64, B), blk, 0, stream>>>(
      x, ao_s, f1_w, f1_b, f1_bn, h_s, nullptr, nullptr, nullptr, B, C, Hm, N);
  conv_bn_lif<1, false, 1><<<gC, blk, 0, stream>>>(
      h_s, nullptr, f2_w, f2_b, f2_bn, nullptr, x, ao_s, (float*)d_out, B, Hm, C, N);
}

// Round 3
// 1685.155 us; speedup vs baseline: 1.2161x; 1.2161x over previous
//
#include <hip/hip_runtime.h>

// numpy-fp32 semantics: explicit fmaf only, no implicit contraction.
#pragma clang fp contract(off)

typedef unsigned char u8;
typedef unsigned int u32;

#define TSTEPS 4

// Fused (1x1 conv) + BN + LIF, fp32, bit-exact ascending-k FMA chain.
// Scalar-W design: 4 waves/block; wave w owns 16 output channels (uniform ->
// W via s_load, SGPR operand of v_fmac); lane = one n column. x staged in
// LDS (double-buffered, global->reg prefetch), read as ds_read_b32 per k
// feeding 16 FMAs/lane -> LDS pipe no longer the bottleneck.
// XMODE: 0 = X1 fp32, 1 = X1 u8 spikes. HASX2: add u8 X2 (fc1: x+attn_out).
// OMODE: 0 = u8 spike out; 1 = fused final out_f32 = (x + ao) + spike.
template <int XMODE, bool HASX2, int OMODE, int CIN>
__global__ __launch_bounds__(256) void conv_bn_lif(
    const void* __restrict__ X1v, const u8* __restrict__ X2,
    const float* __restrict__ Wt, const float* __restrict__ bias,
    const float* __restrict__ bnp,
    u8* __restrict__ Sout,
    const float* __restrict__ Xres, const u8* __restrict__ AOres,
    float* __restrict__ Fout,
    int Bsz, int Cout, int N)
{
  const int tid  = threadIdx.x;
  const int lane = tid & 63;
  const int wid  = __builtin_amdgcn_readfirstlane(tid >> 6);  // wave id 0..3
  const int nBase = blockIdx.x * 64, oBase = blockIdx.y * 64, b = blockIdx.z;
  const int oW = oBase + wid * 16;          // wave-uniform first output chan
  constexpr int KT = CIN >> 5;              // 32-k tiles
  constexpr int TT = TSTEPS * KT;

  __shared__ __align__(16) float Xs[2][32][68];   // [buf][k][n], pad 68

  const float* __restrict__ Wb = Wt + (size_t)oW * CIN;  // uniform base

  // BN constants, correctly-rounded fp32 (double emu exact for add/sqrt/div).
  // All indices wave-uniform -> scalar loads / SGPR residency.
  float sc[16], mn[16], bt[16], bi[16];
  #pragma unroll
  for (int i = 0; i < 16; ++i) {
    int o = oW + i;
    float g  = bnp[0 * Cout + o];
    float be = bnp[1 * Cout + o];
    float m  = bnp[2 * Cout + o];
    float vv = bnp[3 * Cout + o];
    float d_f = (float)((double)vv + (double)1e-5f);
    float s_f = (float)sqrt((double)d_f);
    sc[i] = (float)((double)g / (double)s_f);
    mn[i] = m; bt[i] = be;
    bi[i] = bias ? bias[o] : 0.0f;
  }

  float mem[16], acc[16];
  #pragma unroll
  for (int i = 0; i < 16; ++i) { mem[i] = 0.0f; acc[i] = 0.0f; }

  // x staging loader: thread loads 8 consecutive n of one k-row (32B / 8B).
  const int xRow = tid >> 3;        // 0..31
  const int xC8  = (tid & 7) * 8;   // 0..56

  float4 pxa, pxb;                  // XMODE 0 prefetch regs
  uint2 pxu, pau;                   // XMODE 1 / HASX2

  auto issue = [&](int i) {
    const int tI = i / KT, k0 = (i % KT) << 5;
    const size_t xb = (size_t)(tI * Bsz + b) * CIN * N
                    + (size_t)(k0 + xRow) * N + nBase + xC8;
    if constexpr (XMODE == 0) {
      pxa = *(const float4*)((const float*)X1v + xb);
      pxb = *(const float4*)((const float*)X1v + xb + 4);
    } else {
      pxu = *(const uint2*)((const u8*)X1v + xb);
    }
    if constexpr (HASX2) pau = *(const uint2*)(X2 + xb);
  };

  auto commit = [&](int buf) {
    float xv[8];
    if constexpr (XMODE == 0) {
      xv[0] = pxa.x; xv[1] = pxa.y; xv[2] = pxa.z; xv[3] = pxa.w;
      xv[4] = pxb.x; xv[5] = pxb.y; xv[6] = pxb.z; xv[7] = pxb.w;
    } else {
      #pragma unroll
      for (int j = 0; j < 4; ++j) xv[j]     = (float)((pxu.x >> (8 * j)) & 0xffu);
      #pragma unroll
      for (int j = 0; j < 4; ++j) xv[4 + j] = (float)((pxu.y >> (8 * j)) & 0xffu);
    }
    if constexpr (HASX2) {
      #pragma unroll
      for (int j = 0; j < 4; ++j) xv[j]     = xv[j]     + (float)((pau.x >> (8 * j)) & 0xffu);
      #pragma unroll
      for (int j = 0; j < 4; ++j) xv[4 + j] = xv[4 + j] + (float)((pau.y >> (8 * j)) & 0xffu);
    }
    *(float4*)&Xs[buf][xRow][xC8]     = make_float4(xv[0], xv[1], xv[2], xv[3]);
    *(float4*)&Xs[buf][xRow][xC8 + 4] = make_float4(xv[4], xv[5], xv[6], xv[7]);
  };

  issue(0);
  commit(0);
  __syncthreads();

  for (int tt = 0; tt < TT; ++tt) {
    const int buf = tt & 1;
    const int k0 = (tt % KT) << 5;        // W k-offset of this tile (uniform)
    if (tt + 1 < TT) issue(tt + 1);       // overlap global latency

    #pragma unroll
    for (int kb = 0; kb < 32; kb += 4) {  // ascending k, bit-exact chain
      float xq[4];
      #pragma unroll
      for (int kk = 0; kk < 4; ++kk) xq[kk] = Xs[buf][kb + kk][lane];
      #pragma unroll
      for (int i = 0; i < 16; ++i) {
        const size_t wrow = (size_t)i * CIN + k0 + kb;   // uniform -> s_load
        float w0 = Wb[wrow + 0], w1 = Wb[wrow + 1];
        float w2 = Wb[wrow + 2], w3 = Wb[wrow + 3];
        acc[i] = fmaf(w0, xq[0], acc[i]);
        acc[i] = fmaf(w1, xq[1], acc[i]);
        acc[i] = fmaf(w2, xq[2], acc[i]);
        acc[i] = fmaf(w3, xq[3], acc[i]);
      }
    }

    if ((tt % KT) == KT - 1) {
      // epilogue for timestep t (identical op order to the verified kernel)
      const int t = tt / KT;
      const size_t sbase = (size_t)(t * Bsz + b) * Cout * N;
      #pragma unroll
      for (int i = 0; i < 16; ++i) {
        const size_t rb = sbase + (size_t)(oW + i) * N + nBase + lane;
        float y = acc[i];
        if (bias) y = y + bi[i];
        float t1 = y - mn[i];
        float t2 = t1 * sc[i];
        y = t2 + bt[i];
        float m2 = mem[i];
        float dd = y - m2;
        m2 = m2 + dd * 0.5f;
        bool sp = (m2 - 0.5f) > 0.0f;
        mem[i] = sp ? 0.0f : m2;
        acc[i] = 0.0f;
        if constexpr (OMODE == 0) {
          Sout[rb] = sp ? (u8)1 : (u8)0;
        } else {
          float xr = Xres[rb];
          float av = (float)AOres[rb];
          float s = sp ? 1.0f : 0.0f;
          float xn = xr + av;
          Fout[rb] = xn + s;
        }
      }
    }

    __syncthreads();
    if (tt + 1 < TT) commit((tt + 1) & 1);
    __syncthreads();
  }
}

// Attention + attn-LIF, q @ (k^T v): integer-exact (unchanged, verified).
__global__ __launch_bounds__(256) void attn_lif(
    const u8* __restrict__ Qs, const u8* __restrict__ Ks,
    const u8* __restrict__ Vs, u8* __restrict__ Rs,
    int Bsz, int C, int N)
{
  const int tid = threadIdx.x;
  const int h = blockIdx.x & 15;
  const int b = blockIdx.x >> 4;

  __shared__ u8 qs[16][528];
  __shared__ u8 ks[16][528];
  __shared__ u8 vs[16][528];
  __shared__ int Gs[16][17];

  const int eG = tid >> 4;
  const int dG = tid & 15;
  const int dR = tid >> 4;
  const int nR0 = tid & 15;

  float mem[32];
  #pragma unroll
  for (int i = 0; i < 32; ++i) mem[i] = 0.0f;

  for (int t = 0; t < TSTEPS; ++t) {
    __syncthreads();
    const size_t base = ((size_t)(t * Bsz + b) * C + h * 16) * N;
    for (int i = 0; i < 32; ++i) {
      int flat = tid + 256 * i;
      int d = flat >> 9, n = flat & 511;
      size_t g = base + (size_t)d * N + n;
      qs[d][n] = Qs[g];
      ks[d][n] = Ks[g];
      vs[d][n] = Vs[g];
    }
    __syncthreads();

    int gi = 0;
    for (int n = 0; n < 512; ++n)
      gi += (int)ks[eG][n] * (int)vs[dG][n];
    Gs[eG][dG] = gi;
    __syncthreads();

    int Greg[16];
    #pragma unroll
    for (int e = 0; e < 16; ++e) Greg[e] = Gs[e][dR];

    const size_t obase = ((size_t)(t * Bsz + b) * C + h * 16 + dR) * N;
    for (int j = 0; j < 32; ++j) {
      int n = nR0 + 16 * j;
      int ri = 0;
      #pragma unroll
      for (int e = 0; e < 16; ++e)
        ri += qs[e][n] ? Greg[e] : 0;
      float r = (float)ri * 0.0625f;
      float m2 = mem[j];
      float d = r - m2;
      m2 = m2 + d * 0.5f;
      float s = (m2 - 0.5f) > 0.0f ? 1.0f : 0.0f;
      mem[j] = (s > 0.0f) ? 0.0f : m2;
      Rs[obase + n] = (s > 0.0f) ? (u8)1 : (u8)0;
    }
  }
}

extern "C" void kernel_launch(void* const* d_in, const int* in_sizes, int n_in,
                              void* d_out, int out_size, void* d_ws, size_t ws_size,
                              hipStream_t stream)
{
  const float* x     = (const float*)d_in[0];
  const float* q_w   = (const float*)d_in[1];
  const float* q_bn  = (const float*)d_in[2];
  const float* k_w   = (const float*)d_in[3];
  const float* k_bn  = (const float*)d_in[4];
  const float* v_w   = (const float*)d_in[5];
  const float* v_bn  = (const float*)d_in[6];
  const float* p_w   = (const float*)d_in[7];
  const float* p_bn  = (const float*)d_in[8];
  const float* f1_w  = (const float*)d_in[9];
  const float* f1_b  = (const float*)d_in[10];
  const float* f1_bn = (const float*)d_in[11];
  const float* f2_w  = (const float*)d_in[12];
  const float* f2_b  = (const float*)d_in[13];
  const float* f2_bn = (const float*)d_in[14];

  const int T = 4, B = 16, C = 256, N = 512, Hm = 1024;
  const size_t SZ = (size_t)T * B * C * N;  // u8 spike buffers (8.4 MB)

  // Workspace (u8), peak 5*SZ = 41.9 MB; h (4*SZ) overlays dead q/k/v/r.
  char* ws = (char*)d_ws;
  u8* q_s  = (u8*)(ws + 0 * SZ);
  u8* k_s  = (u8*)(ws + 1 * SZ);
  u8* v_s  = (u8*)(ws + 2 * SZ);
  u8* r_s  = (u8*)(ws + 3 * SZ);
  u8* ao_s = (u8*)(ws + 4 * SZ);
  u8* h_s  = (u8*)(ws + 0 * SZ);

  dim3 blk(256);
  dim3 gC(N / 64, C / 64, B);

  conv_bn_lif<0, false, 0, 256><<<gC, blk, 0, stream>>>(
      x, nullptr, q_w, nullptr, q_bn, q_s, nullptr, nullptr, nullptr, B, C, N);
  conv_bn_lif<0, false, 0, 256><<<gC, blk, 0, stream>>>(
      x, nullptr, k_w, nullptr, k_bn, k_s, nullptr, nullptr, nullptr, B, C, N);
  conv_bn_lif<0, false, 0, 256><<<gC, blk, 0, stream>>>(
      x, nullptr, v_w, nullptr, v_bn, v_s, nullptr, nullptr, nullptr, B, C, N);

  attn_lif<<<dim3(B * 16), blk, 0, stream>>>(q_s, k_s, v_s, r_s, B, C, N);

  conv_bn_lif<1, false, 0, 256><<<gC, blk, 0, stream>>>(
      r_s, nullptr, p_w, nullptr, p_bn, ao_s, nullptr, nullptr, nullptr, B, C, N);
  conv_bn_lif<0, true, 0, 256><<<dim3(N / 64, Hm / 64, B), blk, 0, stream>>>(
      x, ao_s, f1_w, f1_b, f1_bn, h_s, nullptr, nullptr, nullptr, B, Hm, N);
  conv_bn_lif<1, false, 1, 1024><<<gC, blk, 0, stream>>>(
      h_s, nullptr, f2_w, f2_b, f2_bn, nullptr, x, ao_s, (float*)d_out, B, C, N);
}

// Round 4
// 1143.626 us; speedup vs baseline: 1.7919x; 1.4735x over previous
//
#include <hip/hip_runtime.h>

// numpy-fp32 semantics: explicit fmaf only, no implicit contraction.
#pragma clang fp contract(off)

typedef unsigned char u8;
typedef unsigned int u32;

#define TSTEPS 4

// Fused (1x1 conv) + BN + LIF, fp32, bit-exact ascending-k FMA chain.
// Tile: BO=16P outputs x BN=128 n, 256 threads, P x 8 per thread.
// Double-buffered LDS (W transposed [k][o]; X as f32 [k][136] or u8 [k][128]),
// global->reg prefetch of tile i+1 during compute of tile i (R0-verified skel).
// XMODE: 0 = X1 fp32 (split-n frag: q<4 at tx*4, q>=4 at 64+tx*4),
//        1 = X1 u8 spikes (contiguous 8 at tx*8, ds_read_b64 + cvt).
// HASX2: add u8 X2 to X1 at LDS-commit (fc1: x + attn_out, exact).
// OMODE: 0 = u8 spike out; 1 = fused final out_f32 = (x + ao) + spike.
template <int P, int BK, int XMODE, bool HASX2, int OMODE>
__global__ __launch_bounds__(256, 2) void conv_bn_lif(
    const void* __restrict__ X1v, const u8* __restrict__ X2,
    const float* __restrict__ Wt, const float* __restrict__ bias,
    const float* __restrict__ bnp,
    u8* __restrict__ Sout,
    const float* __restrict__ Xres, const u8* __restrict__ AOres,
    float* __restrict__ Fout,
    int Bsz, int Cin, int Cout, int N)
{
  constexpr int BO   = 16 * P;       // block o-tile
  constexpr int BN   = 128;          // block n-tile (fixed)
  constexpr int TPR  = 256 / BK;     // X-loader threads per k-row
  constexpr int FPT  = BN / TPR;     // X elems (f32/u8) per thread
  constexpr int NF4  = FPT / 4;      // float4s (f32) / u32s (u8)
  constexpr int THRO = 256 / BO;     // W-loader threads per o-row
  constexpr int WPAD = (P == 4) ? 4 : 0;
  constexpr int XROWF = BN + 8;      // f32 X row stride (136)

  const int tid = threadIdx.x;
  const int tx = tid & 15, ty = tid >> 4;
  const int nBase = blockIdx.x * BN, oBase = blockIdx.y * BO, b = blockIdx.z;
  const int KT = Cin / BK;
  const int TT = TSTEPS * KT;

  __shared__ __align__(16) float Ws[2][BK][BO + WPAD];
  __shared__ __align__(16) u8 Xraw[(XMODE == 0) ? (2 * BK * XROWF * 4)
                                                : (2 * BK * BN)];
  __shared__ __align__(16) float BnL[BO][4];  // sc, mn, bt, bi

  float* XF = (float*)Xraw;
  u8*    X8 = Xraw;

  // BN constants, correctly-rounded fp32 (double emu exact for add/sqrt/div)
  if (tid < BO) {
    int o = oBase + tid;
    float g  = bnp[0 * Cout + o];
    float be = bnp[1 * Cout + o];
    float m  = bnp[2 * Cout + o];
    float vv = bnp[3 * Cout + o];
    float d_f = (float)((double)vv + (double)1e-5f);
    float s_f = (float)sqrt((double)d_f);
    BnL[tid][0] = (float)((double)g / (double)s_f);
    BnL[tid][1] = m;
    BnL[tid][2] = be;
    BnL[tid][3] = bias ? bias[o] : 0.0f;
  }

  float mem[P][8], acc[P][8];
  #pragma unroll
  for (int p = 0; p < P; ++p)
    #pragma unroll
    for (int q = 0; q < 8; ++q) { mem[p][q] = 0.0f; acc[p][q] = 0.0f; }

  // loader coords
  const int xRow = tid / TPR;
  const int xcF  = (tid % TPR) * FPT;
  const int wO   = tid / THRO;
  const int wK   = (tid % THRO) * 8;

  float4 px[NF4];      // XMODE 0 staging
  u32    pxu[NF4];     // XMODE 1 staging (FPT bytes)
  u32    pau[NF4];     // HASX2 staging  (FPT bytes)
  float4 pwa, pwb;     // W staging (8 k)

  auto issue = [&](int i) {
    const int tI = i / KT, k0 = (i % KT) * BK;
    const size_t xb = (size_t)(tI * Bsz + b) * Cin * N
                    + (size_t)(k0 + xRow) * N + nBase + xcF;
    if constexpr (XMODE == 0) {
      const float* xp = (const float*)X1v + xb;
      #pragma unroll
      for (int f = 0; f < NF4; ++f) px[f] = *(const float4*)(xp + 4 * f);
    } else {
      const u8* xp = (const u8*)X1v + xb;
      if constexpr (NF4 == 4) {
        uint4 u = *(const uint4*)xp;
        pxu[0] = u.x; pxu[1] = u.y; pxu[2] = u.z; pxu[3] = u.w;
      } else {
        uint2 u = *(const uint2*)xp;
        pxu[0] = u.x; pxu[1] = u.y;
      }
    }
    if constexpr (HASX2) {
      const u8* ap = X2 + xb;
      if constexpr (NF4 == 4) {
        uint4 u = *(const uint4*)ap;
        pau[0] = u.x; pau[1] = u.y; pau[2] = u.z; pau[3] = u.w;
      } else {
        uint2 u = *(const uint2*)ap;
        pau[0] = u.x; pau[1] = u.y;
      }
    }
    const size_t wb = (size_t)(oBase + wO) * Cin + k0 + wK;
    pwa = *(const float4*)(Wt + wb);
    pwb = *(const float4*)(Wt + wb + 4);
  };

  auto commit = [&](int bf) {
    if constexpr (XMODE == 0) {
      #pragma unroll
      for (int f = 0; f < NF4; ++f) {
        float4 v = px[f];
        if constexpr (HASX2) {
          u32 a2 = pau[f];
          v.x = v.x + (float)(a2 & 0xffu);
          v.y = v.y + (float)((a2 >> 8) & 0xffu);
          v.z = v.z + (float)((a2 >> 16) & 0xffu);
          v.w = v.w + (float)((a2 >> 24) & 0xffu);
        }
        *(float4*)&XF[((size_t)(bf * BK + xRow)) * XROWF + xcF + 4 * f] = v;
      }
    } else {
      if constexpr (NF4 == 4) {
        *(uint4*)&X8[(size_t)(bf * BK + xRow) * BN + xcF] =
            make_uint4(pxu[0], pxu[1], pxu[2], pxu[3]);
      } else {
        *(uint2*)&X8[(size_t)(bf * BK + xRow) * BN + xcF] =
            make_uint2(pxu[0], pxu[1]);
      }
    }
    Ws[bf][wK + 0][wO] = pwa.x;  Ws[bf][wK + 1][wO] = pwa.y;
    Ws[bf][wK + 2][wO] = pwa.z;  Ws[bf][wK + 3][wO] = pwa.w;
    Ws[bf][wK + 4][wO] = pwb.x;  Ws[bf][wK + 5][wO] = pwb.y;
    Ws[bf][wK + 6][wO] = pwb.z;  Ws[bf][wK + 7][wO] = pwb.w;
  };

  issue(0);
  commit(0);
  __syncthreads();

  for (int tt = 0; tt < TT; ++tt) {
    const int buf = tt & 1;
    if (tt + 1 < TT) issue(tt + 1);   // overlap global latency with compute

    #pragma unroll
    for (int kk = 0; kk < BK; ++kk) { // ascending k, FMA chain (bit-exact)
      float xa[8];
      if constexpr (XMODE == 0) {
        float4 x0 = *(const float4*)&XF[(size_t)(buf * BK + kk) * XROWF + tx * 4];
        float4 x1 = *(const float4*)&XF[(size_t)(buf * BK + kk) * XROWF + 64 + tx * 4];
        xa[0] = x0.x; xa[1] = x0.y; xa[2] = x0.z; xa[3] = x0.w;
        xa[4] = x1.x; xa[5] = x1.y; xa[6] = x1.z; xa[7] = x1.w;
      } else {
        uint2 u = *(const uint2*)&X8[(size_t)(buf * BK + kk) * BN + tx * 8];
        #pragma unroll
        for (int j = 0; j < 4; ++j) xa[j]     = (float)((u.x >> (8 * j)) & 0xffu);
        #pragma unroll
        for (int j = 0; j < 4; ++j) xa[4 + j] = (float)((u.y >> (8 * j)) & 0xffu);
      }
      float wa[P];
      float4 w0 = *(const float4*)&Ws[buf][kk][ty * P];
      wa[0] = w0.x; wa[1] = w0.y; wa[2] = w0.z; wa[3] = w0.w;
      if constexpr (P == 8) {
        float4 w1 = *(const float4*)&Ws[buf][kk][ty * P + 4];
        wa[4] = w1.x; wa[5] = w1.y; wa[6] = w1.z; wa[7] = w1.w;
      }
      #pragma unroll
      for (int p = 0; p < P; ++p)
        #pragma unroll
        for (int q = 0; q < 8; ++q)
          acc[p][q] = fmaf(wa[p], xa[q], acc[p][q]);
    }

    if ((tt % KT) == KT - 1) {
      // epilogue for timestep t (identical op order to the verified kernel)
      const int t = tt / KT;
      const size_t sbase = (size_t)(t * Bsz + b) * Cout * N;
      #pragma unroll
      for (int p = 0; p < P; ++p) {
        const int o = oBase + ty * P + p;
        float4 bv = *(const float4*)&BnL[ty * P + p][0];  // sc, mn, bt, bi
        bool spk[8];
        #pragma unroll
        for (int q = 0; q < 8; ++q) {
          float y = acc[p][q];
          if (bias) y = y + bv.w;
          float t1 = y - bv.y;
          float t2 = t1 * bv.x;
          y = t2 + bv.z;
          float m2 = mem[p][q];
          float dd = y - m2;
          m2 = m2 + dd * 0.5f;
          bool sp = (m2 - 0.5f) > 0.0f;
          mem[p][q] = sp ? 0.0f : m2;
          spk[q] = sp;
          acc[p][q] = 0.0f;
        }
        if constexpr (XMODE == 0) {   // split-n: OMODE==0 only here
          const size_t rb0 = sbase + (size_t)o * N + nBase + tx * 4;
          u32 pk0 = 0, pk1 = 0;
          #pragma unroll
          for (int j = 0; j < 4; ++j) {
            if (spk[j])     pk0 |= (1u << (8 * j));
            if (spk[4 + j]) pk1 |= (1u << (8 * j));
          }
          *(u32*)&Sout[rb0]      = pk0;
          *(u32*)&Sout[rb0 + 64] = pk1;
        } else {
          const size_t rb = sbase + (size_t)o * N + nBase + tx * 8;
          if constexpr (OMODE == 0) {
            u32 pk0 = 0, pk1 = 0;
            #pragma unroll
            for (int j = 0; j < 4; ++j) {
              if (spk[j])     pk0 |= (1u << (8 * j));
              if (spk[4 + j]) pk1 |= (1u << (8 * j));
            }
            *(uint2*)&Sout[rb] = make_uint2(pk0, pk1);
          } else {
            float4 xr0 = *(const float4*)&Xres[rb];
            float4 xr1 = *(const float4*)&Xres[rb + 4];
            uint2 av = *(const uint2*)&AOres[rb];
            float xa4[8] = {xr0.x, xr0.y, xr0.z, xr0.w,
                            xr1.x, xr1.y, xr1.z, xr1.w};
            float o4[8];
            #pragma unroll
            for (int j = 0; j < 4; ++j) {
              float s = spk[j] ? 1.0f : 0.0f;
              float xn = xa4[j] + (float)((av.x >> (8 * j)) & 0xffu);
              o4[j] = xn + s;
            }
            #pragma unroll
            for (int j = 0; j < 4; ++j) {
              float s = spk[4 + j] ? 1.0f : 0.0f;
              float xn = xa4[4 + j] + (float)((av.y >> (8 * j)) & 0xffu);
              o4[4 + j] = xn + s;
            }
            *(float4*)&Fout[rb]     = make_float4(o4[0], o4[1], o4[2], o4[3]);
            *(float4*)&Fout[rb + 4] = make_float4(o4[4], o4[5], o4[6], o4[7]);
          }
        }
      }
    }

    __syncthreads();
    if (tt + 1 < TT) commit((tt + 1) & 1);
    __syncthreads();
  }
}

// Attention + attn-LIF, q @ (k^T v): integer-exact (unchanged, verified).
__global__ __launch_bounds__(256) void attn_lif(
    const u8* __restrict__ Qs, const u8* __restrict__ Ks,
    const u8* __restrict__ Vs, u8* __restrict__ Rs,
    int Bsz, int C, int N)
{
  const int tid = threadIdx.x;
  const int h = blockIdx.x & 15;
  const int b = blockIdx.x >> 4;

  __shared__ u8 qs[16][528];
  __shared__ u8 ks[16][528];
  __shared__ u8 vs[16][528];
  __shared__ int Gs[16][17];

  const int eG = tid >> 4;
  const int dG = tid & 15;
  const int dR = tid >> 4;
  const int nR0 = tid & 15;

  float mem[32];
  #pragma unroll
  for (int i = 0; i < 32; ++i) mem[i] = 0.0f;

  for (int t = 0; t < TSTEPS; ++t) {
    __syncthreads();
    const size_t base = ((size_t)(t * Bsz + b) * C + h * 16) * N;
    for (int i = 0; i < 32; ++i) {
      int flat = tid + 256 * i;
      int d = flat >> 9, n = flat & 511;
      size_t g = base + (size_t)d * N + n;
      qs[d][n] = Qs[g];
      ks[d][n] = Ks[g];
      vs[d][n] = Vs[g];
    }
    __syncthreads();

    int gi = 0;
    for (int n = 0; n < 512; ++n)
      gi += (int)ks[eG][n] * (int)vs[dG][n];
    Gs[eG][dG] = gi;
    __syncthreads();

    int Greg[16];
    #pragma unroll
    for (int e = 0; e < 16; ++e) Greg[e] = Gs[e][dR];

    const size_t obase = ((size_t)(t * Bsz + b) * C + h * 16 + dR) * N;
    for (int j = 0; j < 32; ++j) {
      int n = nR0 + 16 * j;
      int ri = 0;
      #pragma unroll
      for (int e = 0; e < 16; ++e)
        ri += qs[e][n] ? Greg[e] : 0;
      float r = (float)ri * 0.0625f;
      float m2 = mem[j];
      float d = r - m2;
      m2 = m2 + d * 0.5f;
      float s = (m2 - 0.5f) > 0.0f ? 1.0f : 0.0f;
      mem[j] = (s > 0.0f) ? 0.0f : m2;
      Rs[obase + n] = (s > 0.0f) ? (u8)1 : (u8)0;
    }
  }
}

extern "C" void kernel_launch(void* const* d_in, const int* in_sizes, int n_in,
                              void* d_out, int out_size, void* d_ws, size_t ws_size,
                              hipStream_t stream)
{
  const float* x     = (const float*)d_in[0];
  const float* q_w   = (const float*)d_in[1];
  const float* q_bn  = (const float*)d_in[2];
  const float* k_w   = (const float*)d_in[3];
  const float* k_bn  = (const float*)d_in[4];
  const float* v_w   = (const float*)d_in[5];
  const float* v_bn  = (const float*)d_in[6];
  const float* p_w   = (const float*)d_in[7];
  const float* p_bn  = (const float*)d_in[8];
  const float* f1_w  = (const float*)d_in[9];
  const float* f1_b  = (const float*)d_in[10];
  const float* f1_bn = (const float*)d_in[11];
  const float* f2_w  = (const float*)d_in[12];
  const float* f2_b  = (const float*)d_in[13];
  const float* f2_bn = (const float*)d_in[14];

  const int T = 4, B = 16, C = 256, N = 512, Hm = 1024;
  const size_t SZ = (size_t)T * B * C * N;  // u8 spike buffers (8.4 MB)

  // Workspace (u8), peak 5*SZ = 41.9 MB; h (4*SZ) overlays dead q/k/v/r.
  char* ws = (char*)d_ws;
  u8* q_s  = (u8*)(ws + 0 * SZ);
  u8* k_s  = (u8*)(ws + 1 * SZ);
  u8* v_s  = (u8*)(ws + 2 * SZ);
  u8* r_s  = (u8*)(ws + 3 * SZ);
  u8* ao_s = (u8*)(ws + 4 * SZ);
  u8* h_s  = (u8*)(ws + 0 * SZ);

  dim3 blk(256);
  dim3 gC64(N / 128, C / 64, B);     // P=4 configs, Cout=256 -> (4,4,16)
  dim3 gF1(N / 128, Hm / 128, B);    // P=8 fc1       -> (4,8,16)

  conv_bn_lif<4, 32, 0, false, 0><<<gC64, blk, 0, stream>>>(
      x, nullptr, q_w, nullptr, q_bn, q_s, nullptr, nullptr, nullptr, B, C, C, N);
  conv_bn_lif<4, 32, 0, false, 0><<<gC64, blk, 0, stream>>>(
      x, nullptr, k_w, nullptr, k_bn, k_s, nullptr, nullptr, nullptr, B, C, C, N);
  conv_bn_lif<4, 32, 0, false, 0><<<gC64, blk, 0, stream>>>(
      x, nullptr, v_w, nullptr, v_bn, v_s, nullptr, nullptr, nullptr, B, C, C, N);

  attn_lif<<<dim3(B * 16), blk, 0, stream>>>(q_s, k_s, v_s, r_s, B, C, N);

  conv_bn_lif<4, 32, 1, false, 0><<<gC64, blk, 0, stream>>>(
      r_s, nullptr, p_w, nullptr, p_bn, ao_s, nullptr, nullptr, nullptr, B, C, C, N);
  conv_bn_lif<8, 16, 0, true, 0><<<gF1, blk, 0, stream>>>(
      x, ao_s, f1_w, f1_b, f1_bn, h_s, nullptr, nullptr, nullptr, B, C, Hm, N);
  conv_bn_lif<4, 32, 1, false, 1><<<gC64, blk, 0, stream>>>(
      h_s, nullptr, f2_w, f2_b, f2_bn, nullptr, x, ao_s, (float*)d_out, B, Hm, C, N);
}

// Round 5
// 1049.879 us; speedup vs baseline: 1.9519x; 1.0893x over previous
//
#include <hip/hip_runtime.h>

// numpy-fp32 semantics: explicit fmaf only, no implicit contraction.
#pragma clang fp contract(off)

typedef unsigned char u8;
typedef unsigned int u32;

#define TSTEPS 4

// Fused (1x1 conv) + BN + LIF, fp32, bit-exact ascending-k FMA chain.
// Tile: BO=16P outputs x BN=128 n, 256 threads, P x 8 per thread.
// Double-buffered LDS (W transposed [k][o]; X as f32 [k][136] or u8 [k][128]),
// global->reg prefetch of tile i+1 during compute of tile i (R0-verified skel).
// NOTE: no min-waves clause in launch_bounds -- a ",2" caps VGPR at 128 and
// forces scratch spills (R4: 370MB of spill writes on fc1).
// XMODE: 0 = X1 fp32 (split-n frag: q<4 at tx*4, q>=4 at 64+tx*4),
//        1 = X1 u8 spikes (contiguous 8 at tx*8, ds_read_b64 + cvt).
// HASX2: add u8 X2 to X1 at LDS-commit (fc1: x + attn_out, exact).
// OMODE: 0 = u8 spike out; 1 = fused final out_f32 = (x + ao) + spike.
template <int P, int BK, int XMODE, bool HASX2, int OMODE>
__global__ __launch_bounds__(256) void conv_bn_lif(
    const void* __restrict__ X1v, const u8* __restrict__ X2,
    const float* __restrict__ Wt, const float* __restrict__ bias,
    const float* __restrict__ bnp,
    u8* __restrict__ Sout,
    const float* __restrict__ Xres, const u8* __restrict__ AOres,
    float* __restrict__ Fout,
    int Bsz, int Cin, int Cout, int N)
{
  constexpr int BO   = 16 * P;       // block o-tile
  constexpr int BN   = 128;          // block n-tile (fixed)
  constexpr int TPR  = 256 / BK;     // X-loader threads per k-row
  constexpr int FPT  = BN / TPR;     // X elems (f32/u8) per thread
  constexpr int NF4  = FPT / 4;      // float4s (f32) / u32s (u8)
  constexpr int THRO = 256 / BO;     // W-loader threads per o-row
  constexpr int WPAD = (P == 4) ? 4 : 0;
  constexpr int XROWF = BN + 8;      // f32 X row stride (136)

  const int tid = threadIdx.x;
  const int tx = tid & 15, ty = tid >> 4;
  const int nBase = blockIdx.x * BN, oBase = blockIdx.y * BO, b = blockIdx.z;
  const int KT = Cin / BK;
  const int TT = TSTEPS * KT;

  __shared__ __align__(16) float Ws[2][BK][BO + WPAD];
  __shared__ __align__(16) u8 Xraw[(XMODE == 0) ? (2 * BK * XROWF * 4)
                                                : (2 * BK * BN)];
  __shared__ __align__(16) float BnL[BO][4];  // sc, mn, bt, bi

  float* XF = (float*)Xraw;
  u8*    X8 = Xraw;

  // BN constants, correctly-rounded fp32 (double emu exact for add/sqrt/div)
  if (tid < BO) {
    int o = oBase + tid;
    float g  = bnp[0 * Cout + o];
    float be = bnp[1 * Cout + o];
    float m  = bnp[2 * Cout + o];
    float vv = bnp[3 * Cout + o];
    float d_f = (float)((double)vv + (double)1e-5f);
    float s_f = (float)sqrt((double)d_f);
    BnL[tid][0] = (float)((double)g / (double)s_f);
    BnL[tid][1] = m;
    BnL[tid][2] = be;
    BnL[tid][3] = bias ? bias[o] : 0.0f;
  }

  float mem[P][8], acc[P][8];
  #pragma unroll
  for (int p = 0; p < P; ++p)
    #pragma unroll
    for (int q = 0; q < 8; ++q) { mem[p][q] = 0.0f; acc[p][q] = 0.0f; }

  // loader coords
  const int xRow = tid / TPR;
  const int xcF  = (tid % TPR) * FPT;
  const int wO   = tid / THRO;
  const int wK   = (tid % THRO) * 8;

  float4 px[NF4];      // XMODE 0 staging
  u32    pxu[NF4];     // XMODE 1 staging (FPT bytes)
  u32    pau[NF4];     // HASX2 staging  (FPT bytes)
  float4 pwa, pwb;     // W staging (8 k)

  auto issue = [&](int i) {
    const int tI = i / KT, k0 = (i % KT) * BK;
    const size_t xb = (size_t)(tI * Bsz + b) * Cin * N
                    + (size_t)(k0 + xRow) * N + nBase + xcF;
    if constexpr (XMODE == 0) {
      const float* xp = (const float*)X1v + xb;
      #pragma unroll
      for (int f = 0; f < NF4; ++f) px[f] = *(const float4*)(xp + 4 * f);
    } else {
      const u8* xp = (const u8*)X1v + xb;
      if constexpr (NF4 == 4) {
        uint4 u = *(const uint4*)xp;
        pxu[0] = u.x; pxu[1] = u.y; pxu[2] = u.z; pxu[3] = u.w;
      } else {
        uint2 u = *(const uint2*)xp;
        pxu[0] = u.x; pxu[1] = u.y;
      }
    }
    if constexpr (HASX2) {
      const u8* ap = X2 + xb;
      if constexpr (NF4 == 4) {
        uint4 u = *(const uint4*)ap;
        pau[0] = u.x; pau[1] = u.y; pau[2] = u.z; pau[3] = u.w;
      } else {
        uint2 u = *(const uint2*)ap;
        pau[0] = u.x; pau[1] = u.y;
      }
    }
    const size_t wb = (size_t)(oBase + wO) * Cin + k0 + wK;
    pwa = *(const float4*)(Wt + wb);
    pwb = *(const float4*)(Wt + wb + 4);
  };

  auto commit = [&](int bf) {
    if constexpr (XMODE == 0) {
      #pragma unroll
      for (int f = 0; f < NF4; ++f) {
        float4 v = px[f];
        if constexpr (HASX2) {
          u32 a2 = pau[f];
          v.x = v.x + (float)(a2 & 0xffu);
          v.y = v.y + (float)((a2 >> 8) & 0xffu);
          v.z = v.z + (float)((a2 >> 16) & 0xffu);
          v.w = v.w + (float)((a2 >> 24) & 0xffu);
        }
        *(float4*)&XF[((size_t)(bf * BK + xRow)) * XROWF + xcF + 4 * f] = v;
      }
    } else {
      if constexpr (NF4 == 4) {
        *(uint4*)&X8[(size_t)(bf * BK + xRow) * BN + xcF] =
            make_uint4(pxu[0], pxu[1], pxu[2], pxu[3]);
      } else {
        *(uint2*)&X8[(size_t)(bf * BK + xRow) * BN + xcF] =
            make_uint2(pxu[0], pxu[1]);
      }
    }
    Ws[bf][wK + 0][wO] = pwa.x;  Ws[bf][wK + 1][wO] = pwa.y;
    Ws[bf][wK + 2][wO] = pwa.z;  Ws[bf][wK + 3][wO] = pwa.w;
    Ws[bf][wK + 4][wO] = pwb.x;  Ws[bf][wK + 5][wO] = pwb.y;
    Ws[bf][wK + 6][wO] = pwb.z;  Ws[bf][wK + 7][wO] = pwb.w;
  };

  issue(0);
  commit(0);
  __syncthreads();

  for (int tt = 0; tt < TT; ++tt) {
    const int buf = tt & 1;
    if (tt + 1 < TT) issue(tt + 1);   // overlap global latency with compute

    #pragma unroll
    for (int kk = 0; kk < BK; ++kk) { // ascending k, FMA chain (bit-exact)
      float xa[8];
      if constexpr (XMODE == 0) {
        float4 x0 = *(const float4*)&XF[(size_t)(buf * BK + kk) * XROWF + tx * 4];
        float4 x1 = *(const float4*)&XF[(size_t)(buf * BK + kk) * XROWF + 64 + tx * 4];
        xa[0] = x0.x; xa[1] = x0.y; xa[2] = x0.z; xa[3] = x0.w;
        xa[4] = x1.x; xa[5] = x1.y; xa[6] = x1.z; xa[7] = x1.w;
      } else {
        uint2 u = *(const uint2*)&X8[(size_t)(buf * BK + kk) * BN + tx * 8];
        #pragma unroll
        for (int j = 0; j < 4; ++j) xa[j]     = (float)((u.x >> (8 * j)) & 0xffu);
        #pragma unroll
        for (int j = 0; j < 4; ++j) xa[4 + j] = (float)((u.y >> (8 * j)) & 0xffu);
      }
      float wa[P];
      float4 w0 = *(const float4*)&Ws[buf][kk][ty * P];
      wa[0] = w0.x; wa[1] = w0.y; wa[2] = w0.z; wa[3] = w0.w;
      if constexpr (P == 8) {
        float4 w1 = *(const float4*)&Ws[buf][kk][ty * P + 4];
        wa[4] = w1.x; wa[5] = w1.y; wa[6] = w1.z; wa[7] = w1.w;
      }
      #pragma unroll
      for (int p = 0; p < P; ++p)
        #pragma unroll
        for (int q = 0; q < 8; ++q)
          acc[p][q] = fmaf(wa[p], xa[q], acc[p][q]);
    }

    if ((tt % KT) == KT - 1) {
      // epilogue for timestep t (identical op order to the verified kernel)
      const int t = tt / KT;
      const size_t sbase = (size_t)(t * Bsz + b) * Cout * N;
      #pragma unroll
      for (int p = 0; p < P; ++p) {
        const int o = oBase + ty * P + p;
        float4 bv = *(const float4*)&BnL[ty * P + p][0];  // sc, mn, bt, bi
        bool spk[8];
        #pragma unroll
        for (int q = 0; q < 8; ++q) {
          float y = acc[p][q];
          if (bias) y = y + bv.w;
          float t1 = y - bv.y;
          float t2 = t1 * bv.x;
          y = t2 + bv.z;
          float m2 = mem[p][q];
          float dd = y - m2;
          m2 = m2 + dd * 0.5f;
          bool sp = (m2 - 0.5f) > 0.0f;
          mem[p][q] = sp ? 0.0f : m2;
          spk[q] = sp;
          acc[p][q] = 0.0f;
        }
        if constexpr (XMODE == 0) {   // split-n: OMODE==0 only here
          const size_t rb0 = sbase + (size_t)o * N + nBase + tx * 4;
          u32 pk0 = 0, pk1 = 0;
          #pragma unroll
          for (int j = 0; j < 4; ++j) {
            if (spk[j])     pk0 |= (1u << (8 * j));
            if (spk[4 + j]) pk1 |= (1u << (8 * j));
          }
          *(u32*)&Sout[rb0]      = pk0;
          *(u32*)&Sout[rb0 + 64] = pk1;
        } else {
          const size_t rb = sbase + (size_t)o * N + nBase + tx * 8;
          if constexpr (OMODE == 0) {
            u32 pk0 = 0, pk1 = 0;
            #pragma unroll
            for (int j = 0; j < 4; ++j) {
              if (spk[j])     pk0 |= (1u << (8 * j));
              if (spk[4 + j]) pk1 |= (1u << (8 * j));
            }
            *(uint2*)&Sout[rb] = make_uint2(pk0, pk1);
          } else {
            float4 xr0 = *(const float4*)&Xres[rb];
            float4 xr1 = *(const float4*)&Xres[rb + 4];
            uint2 av = *(const uint2*)&AOres[rb];
            float xa4[8] = {xr0.x, xr0.y, xr0.z, xr0.w,
                            xr1.x, xr1.y, xr1.z, xr1.w};
            float o4[8];
            #pragma unroll
            for (int j = 0; j < 4; ++j) {
              float s = spk[j] ? 1.0f : 0.0f;
              float xn = xa4[j] + (float)((av.x >> (8 * j)) & 0xffu);
              o4[j] = xn + s;
            }
            #pragma unroll
            for (int j = 0; j < 4; ++j) {
              float s = spk[4 + j] ? 1.0f : 0.0f;
              float xn = xa4[4 + j] + (float)((av.y >> (8 * j)) & 0xffu);
              o4[4 + j] = xn + s;
            }
            *(float4*)&Fout[rb]     = make_float4(o4[0], o4[1], o4[2], o4[3]);
            *(float4*)&Fout[rb + 4] = make_float4(o4[4], o4[5], o4[6], o4[7]);
          }
        }
      }
    }

    __syncthreads();
    if (tt + 1 < TT) commit((tt + 1) & 1);
    __syncthreads();
  }
}

// Attention + attn-LIF, q @ (k^T v): integer-exact (unchanged, verified).
__global__ __launch_bounds__(256) void attn_lif(
    const u8* __restrict__ Qs, const u8* __restrict__ Ks,
    const u8* __restrict__ Vs, u8* __restrict__ Rs,
    int Bsz, int C, int N)
{
  const int tid = threadIdx.x;
  const int h = blockIdx.x & 15;
  const int b = blockIdx.x >> 4;

  __shared__ u8 qs[16][528];
  __shared__ u8 ks[16][528];
  __shared__ u8 vs[16][528];
  __shared__ int Gs[16][17];

  const int eG = tid >> 4;
  const int dG = tid & 15;
  const int dR = tid >> 4;
  const int nR0 = tid & 15;

  float mem[32];
  #pragma unroll
  for (int i = 0; i < 32; ++i) mem[i] = 0.0f;

  for (int t = 0; t < TSTEPS; ++t) {
    __syncthreads();
    const size_t base = ((size_t)(t * Bsz + b) * C + h * 16) * N;
    for (int i = 0; i < 32; ++i) {
      int flat = tid + 256 * i;
      int d = flat >> 9, n = flat & 511;
      size_t g = base + (size_t)d * N + n;
      qs[d][n] = Qs[g];
      ks[d][n] = Ks[g];
      vs[d][n] = Vs[g];
    }
    __syncthreads();

    int gi = 0;
    for (int n = 0; n < 512; ++n)
      gi += (int)ks[eG][n] * (int)vs[dG][n];
    Gs[eG][dG] = gi;
    __syncthreads();

    int Greg[16];
    #pragma unroll
    for (int e = 0; e < 16; ++e) Greg[e] = Gs[e][dR];

    const size_t obase = ((size_t)(t * Bsz + b) * C + h * 16 + dR) * N;
    for (int j = 0; j < 32; ++j) {
      int n = nR0 + 16 * j;
      int ri = 0;
      #pragma unroll
      for (int e = 0; e < 16; ++e)
        ri += qs[e][n] ? Greg[e] : 0;
      float r = (float)ri * 0.0625f;
      float m2 = mem[j];
      float d = r - m2;
      m2 = m2 + d * 0.5f;
      float s = (m2 - 0.5f) > 0.0f ? 1.0f : 0.0f;
      mem[j] = (s > 0.0f) ? 0.0f : m2;
      Rs[obase + n] = (s > 0.0f) ? (u8)1 : (u8)0;
    }
  }
}

extern "C" void kernel_launch(void* const* d_in, const int* in_sizes, int n_in,
                              void* d_out, int out_size, void* d_ws, size_t ws_size,
                              hipStream_t stream)
{
  const float* x     = (const float*)d_in[0];
  const float* q_w   = (const float*)d_in[1];
  const float* q_bn  = (const float*)d_in[2];
  const float* k_w   = (const float*)d_in[3];
  const float* k_bn  = (const float*)d_in[4];
  const float* v_w   = (const float*)d_in[5];
  const float* v_bn  = (const float*)d_in[6];
  const float* p_w   = (const float*)d_in[7];
  const float* p_bn  = (const float*)d_in[8];
  const float* f1_w  = (const float*)d_in[9];
  const float* f1_b  = (const float*)d_in[10];
  const float* f1_bn = (const float*)d_in[11];
  const float* f2_w  = (const float*)d_in[12];
  const float* f2_b  = (const float*)d_in[13];
  const float* f2_bn = (const float*)d_in[14];

  const int T = 4, B = 16, C = 256, N = 512, Hm = 1024;
  const size_t SZ = (size_t)T * B * C * N;  // u8 spike buffers (8.4 MB)

  // Workspace (u8), peak 5*SZ = 41.9 MB; h (4*SZ) overlays dead q/k/v/r.
  char* ws = (char*)d_ws;
  u8* q_s  = (u8*)(ws + 0 * SZ);
  u8* k_s  = (u8*)(ws + 1 * SZ);
  u8* v_s  = (u8*)(ws + 2 * SZ);
  u8* r_s  = (u8*)(ws + 3 * SZ);
  u8* ao_s = (u8*)(ws + 4 * SZ);
  u8* h_s  = (u8*)(ws + 0 * SZ);

  dim3 blk(256);
  dim3 gC64(N / 128, C / 64, B);     // P=4, Cout=256  -> (4,4,16)
  dim3 gF1(N / 128, Hm / 64, B);     // P=4, Cout=1024 -> (4,16,16)

  conv_bn_lif<4, 32, 0, false, 0><<<gC64, blk, 0, stream>>>(
      x, nullptr, q_w, nullptr, q_bn, q_s, nullptr, nullptr, nullptr, B, C, C, N);
  conv_bn_lif<4, 32, 0, false, 0><<<gC64, blk, 0, stream>>>(
      x, nullptr, k_w, nullptr, k_bn, k_s, nullptr, nullptr, nullptr, B, C, C, N);
  conv_bn_lif<4, 32, 0, false, 0><<<gC64, blk, 0, stream>>>(
      x, nullptr, v_w, nullptr, v_bn, v_s, nullptr, nullptr, nullptr, B, C, C, N);

  attn_lif<<<dim3(B * 16), blk, 0, stream>>>(q_s, k_s, v_s, r_s, B, C, N);

  conv_bn_lif<4, 32, 1, false, 0><<<gC64, blk, 0, stream>>>(
      r_s, nullptr, p_w, nullptr, p_bn, ao_s, nullptr, nullptr, nullptr, B, C, C, N);
  conv_bn_lif<4, 32, 0, true, 0><<<gF1, blk, 0, stream>>>(
      x, ao_s, f1_w, f1_b, f1_bn, h_s, nullptr, nullptr, nullptr, B, C, Hm, N);
  conv_bn_lif<4, 32, 1, false, 1><<<gC64, blk, 0, stream>>>(
      h_s, nullptr, f2_w, f2_b, f2_bn, nullptr, x, ao_s, (float*)d_out, B, Hm, C, N);
}

// Round 6
// 985.128 us; speedup vs baseline: 2.0802x; 1.0657x over previous
//
#include <hip/hip_runtime.h>

// numpy-fp32 semantics: explicit fmaf only, no implicit contraction.
#pragma clang fp contract(off)

typedef unsigned char u8;
typedef unsigned int u32;

#define TSTEPS 4

// Fused (1x1 conv) + BN + LIF, fp32, bit-exact ascending-k FMA chain.
// Tile: BO=16P outputs x BN=128 n, 256 threads, P x 8 per thread.
// Double-buffered LDS (W transposed [k][o]; X as f32 [k][136] or u8 [k][128]),
// global->reg prefetch of tile i+1 during compute of tile i.
// NSEL=3: one dispatch computes 3 weight-sets (QKV share X; blockIdx.y =
// sel * (Cout/BO) + o-tile) -> 3 blocks/CU instead of 1 (occupancy fix).
// P picks per-thread o-rows: 2 (32o blocks: proj/fc2 -> 512-block grids),
// 4 (64o, the R0-verified config), 8 (128o: fc1).
// NOTE: no min-waves clause -- a ",2" caps VGPR at 128 -> spills (R4).
// XMODE: 0 = X1 fp32 (split-n frag q<4 at tx*4, q>=4 at 64+tx*4),
//        1 = X1 u8 spikes (contiguous 8 at tx*8, ds_read_b64 + cvt).
// HASX2: add u8 X2 to X1 at LDS-commit (fc1: x + attn_out, exact).
// OMODE: 0 = u8 spike out; 1 = fused final out_f32 = (x + ao) + spike.
template <int P, int BK, int XMODE, bool HASX2, int OMODE, int NSEL>
__global__ __launch_bounds__(256) void conv_bn_lif(
    const void* __restrict__ X1v, const u8* __restrict__ X2,
    const float* __restrict__ W0, const float* __restrict__ W1,
    const float* __restrict__ W2, const float* __restrict__ bias,
    const float* __restrict__ bn0, const float* __restrict__ bn1,
    const float* __restrict__ bn2,
    u8* __restrict__ S0, u8* __restrict__ S1, u8* __restrict__ S2,
    const float* __restrict__ Xres, const u8* __restrict__ AOres,
    float* __restrict__ Fout,
    int Bsz, int Cin, int Cout, int N)
{
  constexpr int BO   = 16 * P;       // block o-tile
  constexpr int BN   = 128;          // block n-tile (fixed)
  constexpr int TPR  = 256 / BK;     // X-loader threads per k-row (8)
  constexpr int FPT  = BN / TPR;     // X elems per thread (16)
  constexpr int NF4  = FPT / 4;      // 4
  static_assert(NF4 == 4, "loader assumes 16 elems/thread");
  constexpr int WPT  = BO * BK / 256;  // W elems per thread (4/8/16)
  constexpr int NW4  = WPT / 4;        // 1/2/4
  constexpr int TPW  = BK / WPT;       // threads per W o-row (8/4/2)
  constexpr int WPAD = (P == 4) ? 4 : (P == 2) ? 2 : 0;
  constexpr int WROW = BO + WPAD;
  constexpr int XROWF = BN + 8;      // f32 X row stride (136)

  const int tid = threadIdx.x;
  const int tx = tid & 15, ty = tid >> 4;
  const int nBase = blockIdx.x * BN, b = blockIdx.z;

  int sel, oBase;
  if constexpr (NSEL == 3) {
    const int oT = gridDim.y / 3;          // o-tiles per weight-set
    sel = blockIdx.y / oT;
    oBase = (blockIdx.y - sel * oT) * BO;
  } else {
    sel = 0;
    oBase = blockIdx.y * BO;
  }
  const float* __restrict__ Wt  = (sel == 0) ? W0 : (sel == 1) ? W1 : W2;
  const float* __restrict__ bnp = (sel == 0) ? bn0 : (sel == 1) ? bn1 : bn2;
  u8* __restrict__ Sout         = (sel == 0) ? S0 : (sel == 1) ? S1 : S2;

  const int KT = Cin / BK;
  const int TT = TSTEPS * KT;

  __shared__ __align__(16) float Ws[2][BK][WROW];
  __shared__ __align__(16) u8 Xraw[(XMODE == 0) ? (2 * BK * XROWF * 4)
                                                : (2 * BK * BN)];
  __shared__ __align__(16) float BnL[BO][4];  // sc, mn, bt, bi

  float* XF = (float*)Xraw;
  u8*    X8 = Xraw;

  // BN constants, correctly-rounded fp32 (double emu exact for add/sqrt/div)
  if (tid < BO) {
    int o = oBase + tid;
    float g  = bnp[0 * Cout + o];
    float be = bnp[1 * Cout + o];
    float m  = bnp[2 * Cout + o];
    float vv = bnp[3 * Cout + o];
    float d_f = (float)((double)vv + (double)1e-5f);
    float s_f = (float)sqrt((double)d_f);
    BnL[tid][0] = (float)((double)g / (double)s_f);
    BnL[tid][1] = m;
    BnL[tid][2] = be;
    BnL[tid][3] = bias ? bias[o] : 0.0f;
  }

  float mem[P][8], acc[P][8];
  #pragma unroll
  for (int p = 0; p < P; ++p)
    #pragma unroll
    for (int q = 0; q < 8; ++q) { mem[p][q] = 0.0f; acc[p][q] = 0.0f; }

  // loader coords
  const int xRow = tid / TPR;          // 0..BK-1
  const int xcF  = (tid % TPR) * FPT;  // 0..112
  const int wO   = tid / TPW;          // 0..BO-1
  const int wK   = (tid % TPW) * WPT;  // 0..BK-WPT

  float4 px[NF4];      // XMODE 0 staging
  u32    pxu[NF4];     // XMODE 1 staging (16 u8)
  u32    pau[NF4];     // HASX2 staging  (16 u8)
  float4 pw[NW4];      // W staging (WPT k)

  auto issue = [&](int i) {
    const int tI = i / KT, k0 = (i % KT) * BK;
    const size_t xb = (size_t)(tI * Bsz + b) * Cin * N
                    + (size_t)(k0 + xRow) * N + nBase + xcF;
    if constexpr (XMODE == 0) {
      const float* xp = (const float*)X1v + xb;
      #pragma unroll
      for (int f = 0; f < NF4; ++f) px[f] = *(const float4*)(xp + 4 * f);
    } else {
      uint4 u = *(const uint4*)((const u8*)X1v + xb);
      pxu[0] = u.x; pxu[1] = u.y; pxu[2] = u.z; pxu[3] = u.w;
    }
    if constexpr (HASX2) {
      uint4 u = *(const uint4*)(X2 + xb);
      pau[0] = u.x; pau[1] = u.y; pau[2] = u.z; pau[3] = u.w;
    }
    const size_t wb = (size_t)(oBase + wO) * Cin + k0 + wK;
    #pragma unroll
    for (int f = 0; f < NW4; ++f) pw[f] = *(const float4*)(Wt + wb + 4 * f);
  };

  auto commit = [&](int bf) {
    if constexpr (XMODE == 0) {
      #pragma unroll
      for (int f = 0; f < NF4; ++f) {
        float4 v = px[f];
        if constexpr (HASX2) {
          u32 a2 = pau[f];
          v.x = v.x + (float)(a2 & 0xffu);
          v.y = v.y + (float)((a2 >> 8) & 0xffu);
          v.z = v.z + (float)((a2 >> 16) & 0xffu);
          v.w = v.w + (float)((a2 >> 24) & 0xffu);
        }
        *(float4*)&XF[((size_t)(bf * BK + xRow)) * XROWF + xcF + 4 * f] = v;
      }
    } else {
      *(uint4*)&X8[(size_t)(bf * BK + xRow) * BN + xcF] =
          make_uint4(pxu[0], pxu[1], pxu[2], pxu[3]);
    }
    #pragma unroll
    for (int f = 0; f < NW4; ++f) {
      Ws[bf][wK + 4 * f + 0][wO] = pw[f].x;
      Ws[bf][wK + 4 * f + 1][wO] = pw[f].y;
      Ws[bf][wK + 4 * f + 2][wO] = pw[f].z;
      Ws[bf][wK + 4 * f + 3][wO] = pw[f].w;
    }
  };

  issue(0);
  commit(0);
  __syncthreads();

  for (int tt = 0; tt < TT; ++tt) {
    const int buf = tt & 1;
    if (tt + 1 < TT) issue(tt + 1);   // overlap global latency with compute

    #pragma unroll
    for (int kk = 0; kk < BK; ++kk) { // ascending k, FMA chain (bit-exact)
      float xa[8];
      if constexpr (XMODE == 0) {
        float4 x0 = *(const float4*)&XF[(size_t)(buf * BK + kk) * XROWF + tx * 4];
        float4 x1 = *(const float4*)&XF[(size_t)(buf * BK + kk) * XROWF + 64 + tx * 4];
        xa[0] = x0.x; xa[1] = x0.y; xa[2] = x0.z; xa[3] = x0.w;
        xa[4] = x1.x; xa[5] = x1.y; xa[6] = x1.z; xa[7] = x1.w;
      } else {
        uint2 u = *(const uint2*)&X8[(size_t)(buf * BK + kk) * BN + tx * 8];
        #pragma unroll
        for (int j = 0; j < 4; ++j) xa[j]     = (float)((u.x >> (8 * j)) & 0xffu);
        #pragma unroll
        for (int j = 0; j < 4; ++j) xa[4 + j] = (float)((u.y >> (8 * j)) & 0xffu);
      }
      float wa[P];
      if constexpr (P == 2) {
        float2 w0 = *(const float2*)&Ws[buf][kk][ty * 2];
        wa[0] = w0.x; wa[1] = w0.y;
      } else {
        float4 w0 = *(const float4*)&Ws[buf][kk][ty * P];
        wa[0] = w0.x; wa[1] = w0.y; wa[2] = w0.z; wa[3] = w0.w;
        if constexpr (P == 8) {
          float4 w1 = *(const float4*)&Ws[buf][kk][ty * P + 4];
          wa[4] = w1.x; wa[5] = w1.y; wa[6] = w1.z; wa[7] = w1.w;
        }
      }
      #pragma unroll
      for (int p = 0; p < P; ++p)
        #pragma unroll
        for (int q = 0; q < 8; ++q)
          acc[p][q] = fmaf(wa[p], xa[q], acc[p][q]);
    }

    if ((tt % KT) == KT - 1) {
      // epilogue for timestep t (identical op order to the verified kernel)
      const int t = tt / KT;
      const size_t sbase = (size_t)(t * Bsz + b) * Cout * N;
      #pragma unroll
      for (int p = 0; p < P; ++p) {
        const int o = oBase + ty * P + p;
        float4 bv = *(const float4*)&BnL[ty * P + p][0];  // sc, mn, bt, bi
        bool spk[8];
        #pragma unroll
        for (int q = 0; q < 8; ++q) {
          float y = acc[p][q];
          if (bias) y = y + bv.w;
          float t1 = y - bv.y;
          float t2 = t1 * bv.x;
          y = t2 + bv.z;
          float m2 = mem[p][q];
          float dd = y - m2;
          m2 = m2 + dd * 0.5f;
          bool sp = (m2 - 0.5f) > 0.0f;
          mem[p][q] = sp ? 0.0f : m2;
          spk[q] = sp;
          acc[p][q] = 0.0f;
        }
        if constexpr (XMODE == 0) {   // split-n: OMODE==0 only here
          const size_t rb0 = sbase + (size_t)o * N + nBase + tx * 4;
          u32 pk0 = 0, pk1 = 0;
          #pragma unroll
          for (int j = 0; j < 4; ++j) {
            if (spk[j])     pk0 |= (1u << (8 * j));
            if (spk[4 + j]) pk1 |= (1u << (8 * j));
          }
          *(u32*)&Sout[rb0]      = pk0;
          *(u32*)&Sout[rb0 + 64] = pk1;
        } else {
          const size_t rb = sbase + (size_t)o * N + nBase + tx * 8;
          if constexpr (OMODE == 0) {
            u32 pk0 = 0, pk1 = 0;
            #pragma unroll
            for (int j = 0; j < 4; ++j) {
              if (spk[j])     pk0 |= (1u << (8 * j));
              if (spk[4 + j]) pk1 |= (1u << (8 * j));
            }
            *(uint2*)&Sout[rb] = make_uint2(pk0, pk1);
          } else {
            float4 xr0 = *(const float4*)&Xres[rb];
            float4 xr1 = *(const float4*)&Xres[rb + 4];
            uint2 av = *(const uint2*)&AOres[rb];
            float xa4[8] = {xr0.x, xr0.y, xr0.z, xr0.w,
                            xr1.x, xr1.y, xr1.z, xr1.w};
            float o4[8];
            #pragma unroll
            for (int j = 0; j < 4; ++j) {
              float s = spk[j] ? 1.0f : 0.0f;
              float xn = xa4[j] + (float)((av.x >> (8 * j)) & 0xffu);
              o4[j] = xn + s;
            }
            #pragma unroll
            for (int j = 0; j < 4; ++j) {
              float s = spk[4 + j] ? 1.0f : 0.0f;
              float xn = xa4[4 + j] + (float)((av.y >> (8 * j)) & 0xffu);
              o4[4 + j] = xn + s;
            }
            *(float4*)&Fout[rb]     = make_float4(o4[0], o4[1], o4[2], o4[3]);
            *(float4*)&Fout[rb + 4] = make_float4(o4[4], o4[5], o4[6], o4[7]);
          }
        }
      }
    }

    __syncthreads();
    if (tt + 1 < TT) commit((tt + 1) & 1);
    __syncthreads();
  }
}

// Attention + attn-LIF, q @ (k^T v): integer-exact (unchanged, verified).
__global__ __launch_bounds__(256) void attn_lif(
    const u8* __restrict__ Qs, const u8* __restrict__ Ks,
    const u8* __restrict__ Vs, u8* __restrict__ Rs,
    int Bsz, int C, int N)
{
  const int tid = threadIdx.x;
  const int h = blockIdx.x & 15;
  const int b = blockIdx.x >> 4;

  __shared__ u8 qs[16][528];
  __shared__ u8 ks[16][528];
  __shared__ u8 vs[16][528];
  __shared__ int Gs[16][17];

  const int eG = tid >> 4;
  const int dG = tid & 15;
  const int dR = tid >> 4;
  const int nR0 = tid & 15;

  float mem[32];
  #pragma unroll
  for (int i = 0; i < 32; ++i) mem[i] = 0.0f;

  for (int t = 0; t < TSTEPS; ++t) {
    __syncthreads();
    const size_t base = ((size_t)(t * Bsz + b) * C + h * 16) * N;
    for (int i = 0; i < 32; ++i) {
      int flat = tid + 256 * i;
      int d = flat >> 9, n = flat & 511;
      size_t g = base + (size_t)d * N + n;
      qs[d][n] = Qs[g];
      ks[d][n] = Ks[g];
      vs[d][n] = Vs[g];
    }
    __syncthreads();

    int gi = 0;
    for (int n = 0; n < 512; ++n)
      gi += (int)ks[eG][n] * (int)vs[dG][n];
    Gs[eG][dG] = gi;
    __syncthreads();

    int Greg[16];
    #pragma unroll
    for (int e = 0; e < 16; ++e) Greg[e] = Gs[e][dR];

    const size_t obase = ((size_t)(t * Bsz + b) * C + h * 16 + dR) * N;
    for (int j = 0; j < 32; ++j) {
      int n = nR0 + 16 * j;
      int ri = 0;
      #pragma unroll
      for (int e = 0; e < 16; ++e)
        ri += qs[e][n] ? Greg[e] : 0;
      float r = (float)ri * 0.0625f;
      float m2 = mem[j];
      float d = r - m2;
      m2 = m2 + d * 0.5f;
      float s = (m2 - 0.5f) > 0.0f ? 1.0f : 0.0f;
      mem[j] = (s > 0.0f) ? 0.0f : m2;
      Rs[obase + n] = (s > 0.0f) ? (u8)1 : (u8)0;
    }
  }
}

extern "C" void kernel_launch(void* const* d_in, const int* in_sizes, int n_in,
                              void* d_out, int out_size, void* d_ws, size_t ws_size,
                              hipStream_t stream)
{
  const float* x     = (const float*)d_in[0];
  const float* q_w   = (const float*)d_in[1];
  const float* q_bn  = (const float*)d_in[2];
  const float* k_w   = (const float*)d_in[3];
  const float* k_bn  = (const float*)d_in[4];
  const float* v_w   = (const float*)d_in[5];
  const float* v_bn  = (const float*)d_in[6];
  const float* p_w   = (const float*)d_in[7];
  const float* p_bn  = (const float*)d_in[8];
  const float* f1_w  = (const float*)d_in[9];
  const float* f1_b  = (const float*)d_in[10];
  const float* f1_bn = (const float*)d_in[11];
  const float* f2_w  = (const float*)d_in[12];
  const float* f2_b  = (const float*)d_in[13];
  const float* f2_bn = (const float*)d_in[14];

  const int T = 4, B = 16, C = 256, N = 512, Hm = 1024;
  const size_t SZ = (size_t)T * B * C * N;  // u8 spike buffers (8.4 MB)

  // Workspace (u8), peak 5*SZ = 41.9 MB; h (4*SZ) overlays dead q/k/v/r.
  char* ws = (char*)d_ws;
  u8* q_s  = (u8*)(ws + 0 * SZ);
  u8* k_s  = (u8*)(ws + 1 * SZ);
  u8* v_s  = (u8*)(ws + 2 * SZ);
  u8* r_s  = (u8*)(ws + 3 * SZ);
  u8* ao_s = (u8*)(ws + 4 * SZ);
  u8* h_s  = (u8*)(ws + 0 * SZ);

  dim3 blk(256);
  dim3 gQKV(N / 128, 3 * (C / 64), B);   // P=4, fused q/k/v -> (4,12,16)=768
  dim3 gP2(N / 128, C / 32, B);          // P=2, Cout=256    -> (4,8,16)=512
  dim3 gF1(N / 128, Hm / 128, B);        // P=8, Cout=1024   -> (4,8,16)=512

  // Fused QKV: 3 blocks/CU (vs 1), X shared via L2.
  conv_bn_lif<4, 32, 0, false, 0, 3><<<gQKV, blk, 0, stream>>>(
      x, nullptr, q_w, k_w, v_w, nullptr, q_bn, k_bn, v_bn,
      q_s, k_s, v_s, nullptr, nullptr, nullptr, B, C, C, N);

  attn_lif<<<dim3(B * 16), blk, 0, stream>>>(q_s, k_s, v_s, r_s, B, C, N);

  conv_bn_lif<2, 32, 1, false, 0, 1><<<gP2, blk, 0, stream>>>(
      r_s, nullptr, p_w, p_w, p_w, nullptr, p_bn, p_bn, p_bn,
      ao_s, ao_s, ao_s, nullptr, nullptr, nullptr, B, C, C, N);
  conv_bn_lif<8, 32, 0, true, 0, 1><<<gF1, blk, 0, stream>>>(
      x, ao_s, f1_w, f1_w, f1_w, f1_b, f1_bn, f1_bn, f1_bn,
      h_s, h_s, h_s, nullptr, nullptr, nullptr, B, C, Hm, N);
  conv_bn_lif<2, 32, 1, false, 1, 1><<<gP2, blk, 0, stream>>>(
      h_s, nullptr, f2_w, f2_w, f2_w, f2_b, f2_bn, f2_bn, f2_bn,
      nullptr, nullptr, nullptr, x, ao_s, (float*)d_out, B, Hm, C, N);
}

// Round 7
// 979.304 us; speedup vs baseline: 2.0926x; 1.0059x over previous
//
#include <hip/hip_runtime.h>

// numpy-fp32 semantics: explicit fmaf only, no implicit contraction.
#pragma clang fp contract(off)

typedef unsigned char u8;
typedef unsigned int u32;

#define TSTEPS 4

// Single-instruction u8->f32 converts (value-identical to (float)((v>>8j)&0xff);
// hipcc emits v_bfe_u32 + v_cvt_f32_u32 for the C form -- 2x the VALU cost).
__device__ __forceinline__ float cvt_ub0(u32 v) { float f; asm("v_cvt_f32_ubyte0 %0, %1" : "=v"(f) : "v"(v)); return f; }
__device__ __forceinline__ float cvt_ub1(u32 v) { float f; asm("v_cvt_f32_ubyte1 %0, %1" : "=v"(f) : "v"(v)); return f; }
__device__ __forceinline__ float cvt_ub2(u32 v) { float f; asm("v_cvt_f32_ubyte2 %0, %1" : "=v"(f) : "v"(v)); return f; }
__device__ __forceinline__ float cvt_ub3(u32 v) { float f; asm("v_cvt_f32_ubyte3 %0, %1" : "=v"(f) : "v"(v)); return f; }

// Fused (1x1 conv) + BN + LIF, fp32, bit-exact ascending-k FMA chain.
// Tile: BO=16P outputs x BN=128 n, 256 threads, P x 8 per thread.
// Double-buffered LDS (W transposed [k][o]; X as f32 [k][136] or u8 [k][128]),
// global->reg prefetch of tile i+1 during compute of tile i.
// SINGLE barrier per k-tile: with dbuf, commit(buf^1) only conflicts with
// reads that finished before the PREVIOUS barrier (passing barrier at end of
// tt-1 implies compute(buf^1) of tt-1 done) -- the second sync was redundant.
// NSEL=3: one dispatch computes 3 weight-sets (QKV share X; blockIdx.y =
// sel * (Cout/BO) + o-tile) -> 3 blocks/CU instead of 1.
// P picks per-thread o-rows: 2 (proj/fc2), 4 (QKV), 8 (fc1).
// NOTE: no min-waves clause -- a ",2" caps VGPR at 128 -> spills (R4).
// XMODE: 0 = X1 fp32 (split-n frag q<4 at tx*4, q>=4 at 64+tx*4),
//        1 = X1 u8 spikes (contiguous 8 at tx*8, ds_read_b64 + cvt_ub).
// HASX2: add u8 X2 to X1 at LDS-commit (fc1: x + attn_out, exact).
// OMODE: 0 = u8 spike out; 1 = fused final out_f32 = (x + ao) + spike.
template <int P, int BK, int XMODE, bool HASX2, int OMODE, int NSEL>
__global__ __launch_bounds__(256) void conv_bn_lif(
    const void* __restrict__ X1v, const u8* __restrict__ X2,
    const float* __restrict__ W0, const float* __restrict__ W1,
    const float* __restrict__ W2, const float* __restrict__ bias,
    const float* __restrict__ bn0, const float* __restrict__ bn1,
    const float* __restrict__ bn2,
    u8* __restrict__ S0, u8* __restrict__ S1, u8* __restrict__ S2,
    const float* __restrict__ Xres, const u8* __restrict__ AOres,
    float* __restrict__ Fout,
    int Bsz, int Cin, int Cout, int N)
{
  constexpr int BO   = 16 * P;       // block o-tile
  constexpr int BN   = 128;          // block n-tile (fixed)
  constexpr int TPR  = 256 / BK;     // X-loader threads per k-row (8)
  constexpr int FPT  = BN / TPR;     // X elems per thread (16)
  constexpr int NF4  = FPT / 4;      // 4
  static_assert(NF4 == 4, "loader assumes 16 elems/thread");
  constexpr int WPT  = BO * BK / 256;  // W elems per thread (4/8/16)
  constexpr int NW4  = WPT / 4;        // 1/2/4
  constexpr int TPW  = BK / WPT;       // threads per W o-row (8/4/2)
  constexpr int WPAD = (P == 4) ? 4 : (P == 2) ? 2 : 0;
  constexpr int WROW = BO + WPAD;
  constexpr int XROWF = BN + 8;      // f32 X row stride (136)

  const int tid = threadIdx.x;
  const int tx = tid & 15, ty = tid >> 4;
  const int nBase = blockIdx.x * BN, b = blockIdx.z;

  int sel, oBase;
  if constexpr (NSEL == 3) {
    const int oT = gridDim.y / 3;          // o-tiles per weight-set
    sel = blockIdx.y / oT;
    oBase = (blockIdx.y - sel * oT) * BO;
  } else {
    sel = 0;
    oBase = blockIdx.y * BO;
  }
  const float* __restrict__ Wt  = (sel == 0) ? W0 : (sel == 1) ? W1 : W2;
  const float* __restrict__ bnp = (sel == 0) ? bn0 : (sel == 1) ? bn1 : bn2;
  u8* __restrict__ Sout         = (sel == 0) ? S0 : (sel == 1) ? S1 : S2;

  const int KT = Cin / BK;
  const int TT = TSTEPS * KT;

  __shared__ __align__(16) float Ws[2][BK][WROW];
  __shared__ __align__(16) u8 Xraw[(XMODE == 0) ? (2 * BK * XROWF * 4)
                                                : (2 * BK * BN)];
  __shared__ __align__(16) float BnL[BO][4];  // sc, mn, bt, bi

  float* XF = (float*)Xraw;
  u8*    X8 = Xraw;

  // BN constants, correctly-rounded fp32 (double emu exact for add/sqrt/div)
  if (tid < BO) {
    int o = oBase + tid;
    float g  = bnp[0 * Cout + o];
    float be = bnp[1 * Cout + o];
    float m  = bnp[2 * Cout + o];
    float vv = bnp[3 * Cout + o];
    float d_f = (float)((double)vv + (double)1e-5f);
    float s_f = (float)sqrt((double)d_f);
    BnL[tid][0] = (float)((double)g / (double)s_f);
    BnL[tid][1] = m;
    BnL[tid][2] = be;
    BnL[tid][3] = bias ? bias[o] : 0.0f;
  }

  float mem[P][8], acc[P][8];
  #pragma unroll
  for (int p = 0; p < P; ++p)
    #pragma unroll
    for (int q = 0; q < 8; ++q) { mem[p][q] = 0.0f; acc[p][q] = 0.0f; }

  // loader coords
  const int xRow = tid / TPR;          // 0..BK-1
  const int xcF  = (tid % TPR) * FPT;  // 0..112
  const int wO   = tid / TPW;          // 0..BO-1
  const int wK   = (tid % TPW) * WPT;  // 0..BK-WPT

  float4 px[NF4];      // XMODE 0 staging
  u32    pxu[NF4];     // XMODE 1 staging (16 u8)
  u32    pau[NF4];     // HASX2 staging  (16 u8)
  float4 pw[NW4];      // W staging (WPT k)

  auto issue = [&](int i) {
    const int tI = i / KT, k0 = (i % KT) * BK;
    const size_t xb = (size_t)(tI * Bsz + b) * Cin * N
                    + (size_t)(k0 + xRow) * N + nBase + xcF;
    if constexpr (XMODE == 0) {
      const float* xp = (const float*)X1v + xb;
      #pragma unroll
      for (int f = 0; f < NF4; ++f) px[f] = *(const float4*)(xp + 4 * f);
    } else {
      uint4 u = *(const uint4*)((const u8*)X1v + xb);
      pxu[0] = u.x; pxu[1] = u.y; pxu[2] = u.z; pxu[3] = u.w;
    }
    if constexpr (HASX2) {
      uint4 u = *(const uint4*)(X2 + xb);
      pau[0] = u.x; pau[1] = u.y; pau[2] = u.z; pau[3] = u.w;
    }
    const size_t wb = (size_t)(oBase + wO) * Cin + k0 + wK;
    #pragma unroll
    for (int f = 0; f < NW4; ++f) pw[f] = *(const float4*)(Wt + wb + 4 * f);
  };

  auto commit = [&](int bf) {
    if constexpr (XMODE == 0) {
      #pragma unroll
      for (int f = 0; f < NF4; ++f) {
        float4 v = px[f];
        if constexpr (HASX2) {
          u32 a2 = pau[f];
          v.x = v.x + (float)(a2 & 0xffu);
          v.y = v.y + (float)((a2 >> 8) & 0xffu);
          v.z = v.z + (float)((a2 >> 16) & 0xffu);
          v.w = v.w + (float)((a2 >> 24) & 0xffu);
        }
        *(float4*)&XF[((size_t)(bf * BK + xRow)) * XROWF + xcF + 4 * f] = v;
      }
    } else {
      *(uint4*)&X8[(size_t)(bf * BK + xRow) * BN + xcF] =
          make_uint4(pxu[0], pxu[1], pxu[2], pxu[3]);
    }
    #pragma unroll
    for (int f = 0; f < NW4; ++f) {
      Ws[bf][wK + 4 * f + 0][wO] = pw[f].x;
      Ws[bf][wK + 4 * f + 1][wO] = pw[f].y;
      Ws[bf][wK + 4 * f + 2][wO] = pw[f].z;
      Ws[bf][wK + 4 * f + 3][wO] = pw[f].w;
    }
  };

  issue(0);
  commit(0);
  __syncthreads();

  for (int tt = 0; tt < TT; ++tt) {
    const int buf = tt & 1;
    if (tt + 1 < TT) issue(tt + 1);   // overlap global latency with compute

    #pragma unroll
    for (int kk = 0; kk < BK; ++kk) { // ascending k, FMA chain (bit-exact)
      float xa[8];
      if constexpr (XMODE == 0) {
        float4 x0 = *(const float4*)&XF[(size_t)(buf * BK + kk) * XROWF + tx * 4];
        float4 x1 = *(const float4*)&XF[(size_t)(buf * BK + kk) * XROWF + 64 + tx * 4];
        xa[0] = x0.x; xa[1] = x0.y; xa[2] = x0.z; xa[3] = x0.w;
        xa[4] = x1.x; xa[5] = x1.y; xa[6] = x1.z; xa[7] = x1.w;
      } else {
        uint2 u = *(const uint2*)&X8[(size_t)(buf * BK + kk) * BN + tx * 8];
        xa[0] = cvt_ub0(u.x); xa[1] = cvt_ub1(u.x);
        xa[2] = cvt_ub2(u.x); xa[3] = cvt_ub3(u.x);
        xa[4] = cvt_ub0(u.y); xa[5] = cvt_ub1(u.y);
        xa[6] = cvt_ub2(u.y); xa[7] = cvt_ub3(u.y);
      }
      float wa[P];
      if constexpr (P == 2) {
        float2 w0 = *(const float2*)&Ws[buf][kk][ty * 2];
        wa[0] = w0.x; wa[1] = w0.y;
      } else {
        float4 w0 = *(const float4*)&Ws[buf][kk][ty * P];
        wa[0] = w0.x; wa[1] = w0.y; wa[2] = w0.z; wa[3] = w0.w;
        if constexpr (P == 8) {
          float4 w1 = *(const float4*)&Ws[buf][kk][ty * P + 4];
          wa[4] = w1.x; wa[5] = w1.y; wa[6] = w1.z; wa[7] = w1.w;
        }
      }
      #pragma unroll
      for (int p = 0; p < P; ++p)
        #pragma unroll
        for (int q = 0; q < 8; ++q)
          acc[p][q] = fmaf(wa[p], xa[q], acc[p][q]);
    }

    if ((tt % KT) == KT - 1) {
      // epilogue for timestep t (identical op order to the verified kernel)
      const int t = tt / KT;
      const size_t sbase = (size_t)(t * Bsz + b) * Cout * N;
      #pragma unroll
      for (int p = 0; p < P; ++p) {
        const int o = oBase + ty * P + p;
        float4 bv = *(const float4*)&BnL[ty * P + p][0];  // sc, mn, bt, bi
        bool spk[8];
        #pragma unroll
        for (int q = 0; q < 8; ++q) {
          float y = acc[p][q];
          if (bias) y = y + bv.w;
          float t1 = y - bv.y;
          float t2 = t1 * bv.x;
          y = t2 + bv.z;
          float m2 = mem[p][q];
          float dd = y - m2;
          m2 = m2 + dd * 0.5f;
          bool sp = (m2 - 0.5f) > 0.0f;
          mem[p][q] = sp ? 0.0f : m2;
          spk[q] = sp;
          acc[p][q] = 0.0f;
        }
        if constexpr (XMODE == 0) {   // split-n: OMODE==0 only here
          const size_t rb0 = sbase + (size_t)o * N + nBase + tx * 4;
          u32 pk0 = 0, pk1 = 0;
          #pragma unroll
          for (int j = 0; j < 4; ++j) {
            if (spk[j])     pk0 |= (1u << (8 * j));
            if (spk[4 + j]) pk1 |= (1u << (8 * j));
          }
          *(u32*)&Sout[rb0]      = pk0;
          *(u32*)&Sout[rb0 + 64] = pk1;
        } else {
          const size_t rb = sbase + (size_t)o * N + nBase + tx * 8;
          if constexpr (OMODE == 0) {
            u32 pk0 = 0, pk1 = 0;
            #pragma unroll
            for (int j = 0; j < 4; ++j) {
              if (spk[j])     pk0 |= (1u << (8 * j));
              if (spk[4 + j]) pk1 |= (1u << (8 * j));
            }
            *(uint2*)&Sout[rb] = make_uint2(pk0, pk1);
          } else {
            float4 xr0 = *(const float4*)&Xres[rb];
            float4 xr1 = *(const float4*)&Xres[rb + 4];
            uint2 av = *(const uint2*)&AOres[rb];
            float xa4[8] = {xr0.x, xr0.y, xr0.z, xr0.w,
                            xr1.x, xr1.y, xr1.z, xr1.w};
            float o4[8];
            #pragma unroll
            for (int j = 0; j < 4; ++j) {
              float s = spk[j] ? 1.0f : 0.0f;
              float xn = xa4[j] + (float)((av.x >> (8 * j)) & 0xffu);
              o4[j] = xn + s;
            }
            #pragma unroll
            for (int j = 0; j < 4; ++j) {
              float s = spk[4 + j] ? 1.0f : 0.0f;
              float xn = xa4[4 + j] + (float)((av.y >> (8 * j)) & 0xffu);
              o4[4 + j] = xn + s;
            }
            *(float4*)&Fout[rb]     = make_float4(o4[0], o4[1], o4[2], o4[3]);
            *(float4*)&Fout[rb + 4] = make_float4(o4[4], o4[5], o4[6], o4[7]);
          }
        }
      }
    }

    // single barrier per k-tile (see header comment for the safety proof)
    if (tt + 1 < TT) commit((tt + 1) & 1);
    __syncthreads();
  }
}

// Attention + attn-LIF, q @ (k^T v): integer-exact (unchanged, verified).
__global__ __launch_bounds__(256) void attn_lif(
    const u8* __restrict__ Qs, const u8* __restrict__ Ks,
    const u8* __restrict__ Vs, u8* __restrict__ Rs,
    int Bsz, int C, int N)
{
  const int tid = threadIdx.x;
  const int h = blockIdx.x & 15;
  const int b = blockIdx.x >> 4;

  __shared__ u8 qs[16][528];
  __shared__ u8 ks[16][528];
  __shared__ u8 vs[16][528];
  __shared__ int Gs[16][17];

  const int eG = tid >> 4;
  const int dG = tid & 15;
  const int dR = tid >> 4;
  const int nR0 = tid & 15;

  float mem[32];
  #pragma unroll
  for (int i = 0; i < 32; ++i) mem[i] = 0.0f;

  for (int t = 0; t < TSTEPS; ++t) {
    __syncthreads();
    const size_t base = ((size_t)(t * Bsz + b) * C + h * 16) * N;
    for (int i = 0; i < 32; ++i) {
      int flat = tid + 256 * i;
      int d = flat >> 9, n = flat & 511;
      size_t g = base + (size_t)d * N + n;
      qs[d][n] = Qs[g];
      ks[d][n] = Ks[g];
      vs[d][n] = Vs[g];
    }
    __syncthreads();

    int gi = 0;
    for (int n = 0; n < 512; ++n)
      gi += (int)ks[eG][n] * (int)vs[dG][n];
    Gs[eG][dG] = gi;
    __syncthreads();

    int Greg[16];
    #pragma unroll
    for (int e = 0; e < 16; ++e) Greg[e] = Gs[e][dR];

    const size_t obase = ((size_t)(t * Bsz + b) * C + h * 16 + dR) * N;
    for (int j = 0; j < 32; ++j) {
      int n = nR0 + 16 * j;
      int ri = 0;
      #pragma unroll
      for (int e = 0; e < 16; ++e)
        ri += qs[e][n] ? Greg[e] : 0;
      float r = (float)ri * 0.0625f;
      float m2 = mem[j];
      float d = r - m2;
      m2 = m2 + d * 0.5f;
      float s = (m2 - 0.5f) > 0.0f ? 1.0f : 0.0f;
      mem[j] = (s > 0.0f) ? 0.0f : m2;
      Rs[obase + n] = (s > 0.0f) ? (u8)1 : (u8)0;
    }
  }
}

extern "C" void kernel_launch(void* const* d_in, const int* in_sizes, int n_in,
                              void* d_out, int out_size, void* d_ws, size_t ws_size,
                              hipStream_t stream)
{
  const float* x     = (const float*)d_in[0];
  const float* q_w   = (const float*)d_in[1];
  const float* q_bn  = (const float*)d_in[2];
  const float* k_w   = (const float*)d_in[3];
  const float* k_bn  = (const float*)d_in[4];
  const float* v_w   = (const float*)d_in[5];
  const float* v_bn  = (const float*)d_in[6];
  const float* p_w   = (const float*)d_in[7];
  const float* p_bn  = (const float*)d_in[8];
  const float* f1_w  = (const float*)d_in[9];
  const float* f1_b  = (const float*)d_in[10];
  const float* f1_bn = (const float*)d_in[11];
  const float* f2_w  = (const float*)d_in[12];
  const float* f2_b  = (const float*)d_in[13];
  const float* f2_bn = (const float*)d_in[14];

  const int T = 4, B = 16, C = 256, N = 512, Hm = 1024;
  const size_t SZ = (size_t)T * B * C * N;  // u8 spike buffers (8.4 MB)

  // Workspace (u8), peak 5*SZ = 41.9 MB; h (4*SZ) overlays dead q/k/v/r.
  char* ws = (char*)d_ws;
  u8* q_s  = (u8*)(ws + 0 * SZ);
  u8* k_s  = (u8*)(ws + 1 * SZ);
  u8* v_s  = (u8*)(ws + 2 * SZ);
  u8* r_s  = (u8*)(ws + 3 * SZ);
  u8* ao_s = (u8*)(ws + 4 * SZ);
  u8* h_s  = (u8*)(ws + 0 * SZ);

  dim3 blk(256);
  dim3 gQKV(N / 128, 3 * (C / 64), B);   // P=4, fused q/k/v -> (4,12,16)=768
  dim3 gP2(N / 128, C / 32, B);          // P=2, Cout=256    -> (4,8,16)=512
  dim3 gF1(N / 128, Hm / 128, B);        // P=8, Cout=1024   -> (4,8,16)=512

  // Fused QKV: 3 blocks/CU (vs 1), X shared via L2.
  conv_bn_lif<4, 32, 0, false, 0, 3><<<gQKV, blk, 0, stream>>>(
      x, nullptr, q_w, k_w, v_w, nullptr, q_bn, k_bn, v_bn,
      q_s, k_s, v_s, nullptr, nullptr, nullptr, B, C, C, N);

  attn_lif<<<dim3(B * 16), blk, 0, stream>>>(q_s, k_s, v_s, r_s, B, C, N);

  conv_bn_lif<2, 32, 1, false, 0, 1><<<gP2, blk, 0, stream>>>(
      r_s, nullptr, p_w, p_w, p_w, nullptr, p_bn, p_bn, p_bn,
      ao_s, ao_s, ao_s, nullptr, nullptr, nullptr, B, C, C, N);
  conv_bn_lif<8, 32, 0, true, 0, 1><<<gF1, blk, 0, stream>>>(
      x, ao_s, f1_w, f1_w, f1_w, f1_b, f1_bn, f1_bn, f1_bn,
      h_s, h_s, h_s, nullptr, nullptr, nullptr, B, C, Hm, N);
  conv_bn_lif<2, 32, 1, false, 1, 1><<<gP2, blk, 0, stream>>>(
      h_s, nullptr, f2_w, f2_w, f2_w, f2_b, f2_bn, f2_bn, f2_bn,
      nullptr, nullptr, nullptr, x, ao_s, (float*)d_out, B, Hm, C, N);
}